// Round 3
// baseline (646.887 us; speedup 1.0000x reference)
//
#include <hip/hip_runtime.h>
#include <hip/hip_bf16.h>

// Problem constants (fixed by the reference)
constexpr int N_ = 2000;   // nodes
constexpr int E_ = 4096;   // edges
constexpr int H_ = 256;    // hidden
constexpr int KH_ = 128;   // he dim (mlp1 out)
constexpr int NV_ = H_ * KH_; // 32768, V row length — fp8 bytes
constexpr int MPAD_ = 2048;   // padded M for node-side MFMA GEMMs
constexpr int NG_ = 768;      // GRU gate width (3*H)
constexpr float VSCALE = 64.f;     // fp8 scale for V (avoids e4m3 subnormals)
constexpr float VSCALE_INV = 1.f / 64.f;

typedef short bf16x8 __attribute__((ext_vector_type(8)));
typedef float f32x4  __attribute__((ext_vector_type(4)));
typedef float f32x2  __attribute__((ext_vector_type(2)));

__device__ __forceinline__ float bf_lo(unsigned u) { return __uint_as_float(u << 16); }
__device__ __forceinline__ float bf_hi(unsigned u) { return __uint_as_float(u & 0xffff0000u); }
__device__ __forceinline__ short bfbits(float f) {
    __hip_bfloat16 b = __float2bfloat16(f);
    return *(short*)&b;
}

// ---- pipeline sync helpers (T4: counted vmcnt across raw barrier) ----
#define PIPE_WAIT_ENTER(N_OUTST)                                   \
    asm volatile("s_waitcnt vmcnt(" #N_OUTST ")" ::: "memory");    \
    __builtin_amdgcn_s_barrier();                                  \
    asm volatile("" ::: "memory");                                 \
    __builtin_amdgcn_sched_barrier(0);

#define PIPE_EXIT()                                                \
    __builtin_amdgcn_sched_barrier(0);                             \
    asm volatile("" ::: "memory");                                 \
    __builtin_amdgcn_s_barrier();

// out = relu([emb[x], pos] @ lin0_W.T + b); also emits Abf (bf16, zero-padded rows).
__global__ void k_lin0(const int* __restrict__ x, const float* __restrict__ pos,
                       const float* __restrict__ emb, const float* __restrict__ W,
                       const float* __restrict__ b, float* __restrict__ out,
                       __hip_bfloat16* __restrict__ Abf) {
    int n = blockIdx.x, t = threadIdx.x;
    if (n >= N_) { Abf[(size_t)n * H_ + t] = __float2bfloat16(0.f); return; }
    __shared__ float in_p[8];
    if (t < 5) in_p[t] = emb[x[n] * 5 + t];
    else if (t < 8) in_p[t] = pos[n * 3 + (t - 5)];
    __syncthreads();
    float acc = b[t];
#pragma unroll
    for (int i = 0; i < 8; i++) acc += in_p[i] * W[t * 8 + i];
    float v = fmaxf(acc, 0.f);
    out[n * H_ + t] = v;
    Abf[(size_t)n * H_ + t] = __float2bfloat16(v);
}

// he = relu(edge_atr @ mlp1_W.T + b)   grid E, block 128
__global__ void k_he(const float* __restrict__ ea, const float* __restrict__ W,
                     const float* __restrict__ b, float* __restrict__ he) {
    int e = blockIdx.x, t = threadIdx.x;
    __shared__ float a[5];
    if (t < 5) a[t] = ea[e * 5 + t];
    __syncthreads();
    float acc = b[t];
#pragma unroll
    for (int i = 0; i < 5; i++) acc += a[i] * W[t * 5 + i];
    he[e * KH_ + t] = fmaxf(acc, 0.f);
}

// col in-degree (for normalization) + row out-degree (for CSR)
__global__ void k_counts(const int* __restrict__ ei, float* __restrict__ counts,
                         int* __restrict__ deg) {
    int e = blockIdx.x * blockDim.x + threadIdx.x;
    if (e < E_) {
        atomicAdd(&counts[ei[E_ + e]], 1.0f);
        atomicAdd(&deg[ei[e]], 1);
    }
}

// exclusive prefix over deg[0..N_-1] -> rowptr[0..N_]   (1 block, 256 threads)
__global__ void k_scan(const int* __restrict__ deg, int* __restrict__ rowptr) {
    __shared__ int ws[256];
    int t = threadIdx.x;
    int base = t * 8;
    int loc[8];
    int s = 0;
#pragma unroll
    for (int j = 0; j < 8; j++) {
        int idx = base + j;
        int d = (idx < N_) ? deg[idx] : 0;
        loc[j] = s;
        s += d;
    }
    ws[t] = s;
    __syncthreads();
    for (int off2 = 1; off2 < 256; off2 <<= 1) {
        int v = (t >= off2) ? ws[t - off2] : 0;
        __syncthreads();
        ws[t] += v;
        __syncthreads();
    }
    int excl = ws[t] - s;
#pragma unroll
    for (int j = 0; j < 8; j++) {
        int idx = base + j;
        if (idx <= N_) rowptr[idx] = excl + loc[j];
    }
}

// scatter edge ids into row-CSR order
__global__ void k_fill(const int* __restrict__ ei, const int* __restrict__ rowptr,
                       int* __restrict__ wcur, int* __restrict__ eord) {
    int e = blockIdx.x * blockDim.x + threadIdx.x;
    if (e < E_) {
        int r = ei[e];
        int p = atomicAdd(&wcur[r], 1);
        eord[rowptr[r] + p] = e;
    }
}

// Bt[nv][h] = mlp2_W[h*32768 + nv] as bf16 (transpose+convert), once per launch.
// float4 loads, short4 stores.
__global__ void k_trans_bt(const float* __restrict__ W, __hip_bfloat16* __restrict__ Bt) {
    __shared__ float tile[32][68];   // 68: 16B-aligned rows, bank-shifted
    int t = threadIdx.x;
    int n0 = blockIdx.x * 64, k0 = blockIdx.y * 32;
#pragma unroll
    for (int i = 0; i < 2; i++) {
        int idx = t + i * 256;                 // 0..511
        int kk = idx >> 4, nn = (idx & 15) * 4;
        float4 f = *(const float4*)&W[(size_t)(k0 + kk) * NV_ + n0 + nn];
        *(float4*)&tile[kk][nn] = f;
    }
    __syncthreads();
#pragma unroll
    for (int i = 0; i < 2; i++) {
        int idx = t + i * 256;                 // 0..511
        int nn = idx >> 3, k4 = (idx & 7) * 4;
        short4 s;
        s.x = bfbits(tile[k4 + 0][nn]);
        s.y = bfbits(tile[k4 + 1][nn]);
        s.z = bfbits(tile[k4 + 2][nn]);
        s.w = bfbits(tile[k4 + 3][nn]);
        *(short4*)&Bt[(size_t)(n0 + nn) * H_ + k0 + k4] = s;
    }
}

// One-time weight preps (bf16 converts + packed tail B + lin2 pad + mlp2_b transpose).
__global__ void k_prep_w(const float* __restrict__ Wih, const float* __restrict__ Whh,
                         const float* __restrict__ lin1W, const float* __restrict__ l6W1,
                         const float* __restrict__ lin2W, const float* __restrict__ b2,
                         __hip_bfloat16* __restrict__ WihB, __hip_bfloat16* __restrict__ WhhB,
                         __hip_bfloat16* __restrict__ Bpk,
                         __hip_bfloat16* __restrict__ lin2Wb, __hip_bfloat16* __restrict__ BtB) {
    int i = blockIdx.x * 256 + threadIdx.x;     // i < 196608
    if (i < NG_ * H_) {
        WihB[i] = __float2bfloat16(Wih[i]);
        WhhB[i] = __float2bfloat16(Whh[i]);
    }
    Bpk[i] = __float2bfloat16(i < 256 * 512 ? lin1W[i] : l6W1[i - 256 * 512]);
    if (i < 128 * 2 * H_) {
        int r = i >> 8, k = i & 255;
        lin2Wb[i] = __float2bfloat16(r < 242 ? lin2W[r * H_ + k] : 0.f);
        int o = i >> 8, h = i & 255;
        BtB[o * H_ + h] = __float2bfloat16(b2[h * H_ + o]);
    }
}

// Cbf[e] = bf16([h[row[e]], h[col[e]]])   grid E, block 256
__global__ void k_concat(const int* __restrict__ ei, const float* __restrict__ h,
                         __hip_bfloat16* __restrict__ Cbf) {
    int e = blockIdx.x, t = threadIdx.x;
    int r = ei[e], c = ei[E_ + e];
    Cbf[(size_t)e * 512 + t]       = __float2bfloat16(h[(size_t)r * H_ + t]);
    Cbf[(size_t)e * 512 + 256 + t] = __float2bfloat16(h[(size_t)c * H_ + t]);
}

// Generic MFMA GEMM: C(MxN) = A(MxKD bf16) @ Bt(NxKD bf16)^T [+bias][relu].
// Depth-3 pipeline: 3 LDS buffers, steady-state vmcnt(8) (2 stages in flight).
template <int KD, bool RELU, bool OUT_BF16>
__global__ __launch_bounds__(256, 3) void k_gemm_nt(const __hip_bfloat16* __restrict__ A,
                                                    const __hip_bfloat16* __restrict__ Bt,
                                                    float* __restrict__ Cf,
                                                    __hip_bfloat16* __restrict__ Cb,
                                                    const float* __restrict__ bias,
                                                    int ldc, int ncols, int mvalid) {
    __shared__ __align__(16) short As[3][4096];
    __shared__ __align__(16) short Bs[3][4096];
    int t = threadIdx.x;
    int lane = t & 63, wave = t >> 6;
    int wm = wave >> 1, wn = wave & 1;
    int quad = lane >> 4, l16 = lane & 15;
    int row0 = blockIdx.y * 128, col0 = blockIdx.x * 128;

    f32x4 acc[4][4] = {};
    int r_ld = (lane >> 2);
    int koff = (((lane & 3) ^ ((lane >> 3) & 3)) * 8);  // swizzled 16B slot
    int swz = (l16 >> 1) & 3;                           // read-side slot XOR
    constexpr int NST = KD / 32;

    auto stage = [&](int buf, int k0) {
#pragma unroll
        for (int c = 0; c < 4; c++) {
            int q = wave * 4 + c;
            int ch = q & 7;
            int r = ch * 16 + r_ld;
            const __hip_bfloat16* gp;
            short* lp;
            if (q < 8) { gp = A  + (size_t)(row0 + r) * KD + k0 + koff; lp = &As[buf][ch * 512]; }
            else       { gp = Bt + (size_t)(col0 + r) * KD + k0 + koff; lp = &Bs[buf][ch * 512]; }
            __builtin_amdgcn_global_load_lds(
                (const __attribute__((address_space(1))) unsigned int*)(uintptr_t)gp,
                (__attribute__((address_space(3))) unsigned int*)(uintptr_t)lp,
                16, 0, 0);
        }
    };

    stage(0, 0);
    stage(1, 32);
    for (int kk = 0; kk < NST; kk++) {
        int cur = kk % 3;
        if (kk + 2 < NST) {
            stage((kk + 2) % 3, (kk + 2) * 32);
            PIPE_WAIT_ENTER(8)
        } else if (kk + 1 < NST) {
            PIPE_WAIT_ENTER(4)
        } else {
            PIPE_WAIT_ENTER(0)
        }
        bf16x8 a[4], b[4];
#pragma unroll
        for (int i = 0; i < 4; i++)
            a[i] = *(const bf16x8*)&As[cur][(wm * 64 + i * 16 + l16) * 32 + ((quad ^ swz) << 3)];
#pragma unroll
        for (int j = 0; j < 4; j++)
            b[j] = *(const bf16x8*)&Bs[cur][(wn * 64 + j * 16 + l16) * 32 + ((quad ^ swz) << 3)];
#pragma unroll
        for (int i = 0; i < 4; i++)
#pragma unroll
            for (int j = 0; j < 4; j++)
                acc[i][j] = __builtin_amdgcn_mfma_f32_16x16x32_bf16(a[i], b[j], acc[i][j], 0, 0, 0);
        PIPE_EXIT()
    }

#pragma unroll
    for (int i = 0; i < 4; i++) {
        int gm0 = row0 + wm * 64 + i * 16 + quad * 4;
#pragma unroll
        for (int r = 0; r < 4; r++) {
            int gm = gm0 + r;
            if (gm < mvalid) {
#pragma unroll
                for (int j = 0; j < 4; j++) {
                    int col = col0 + wn * 64 + l16 + j * 16;
                    if (col < ncols) {
                        float v = acc[i][j][r];
                        if (bias) v += bias[col];
                        if (RELU) v = fmaxf(v, 0.f);
                        if (OUT_BF16) Cb[(size_t)gm * ldc + col] = __float2bfloat16(v);
                        else          Cf[(size_t)gm * ldc + col] = v;
                    }
                }
            }
        }
    }
}

// Pre-msg pair GEMM (both consume Abf, K=256):
//   blocks x=0..5: gh = Abf @ WhhB^T + bhh  (ldc 768)
//   blocks x=6..7: outb = Abf @ BtB^T       (ldc 256)
__global__ __launch_bounds__(256, 3) void k_gemm_pair(const __hip_bfloat16* __restrict__ Abf,
                                                      const __hip_bfloat16* __restrict__ WhhB,
                                                      const __hip_bfloat16* __restrict__ BtB,
                                                      const float* __restrict__ bhh,
                                                      float* __restrict__ gh,
                                                      float* __restrict__ outb) {
    bool ob = (blockIdx.x >= 6);
    const __hip_bfloat16* Bt = ob ? BtB : WhhB;
    int col0 = ob ? ((int)blockIdx.x - 6) * 128 : (int)blockIdx.x * 128;
    int ldc = ob ? H_ : NG_;
    float* C = ob ? outb : gh;

    __shared__ __align__(16) short As[3][4096];
    __shared__ __align__(16) short Bs[3][4096];
    int t = threadIdx.x;
    int lane = t & 63, wave = t >> 6;
    int wm = wave >> 1, wn = wave & 1;
    int quad = lane >> 4, l16 = lane & 15;
    int row0 = blockIdx.y * 128;

    f32x4 acc[4][4] = {};
    int r_ld = (lane >> 2);
    int koff = (((lane & 3) ^ ((lane >> 3) & 3)) * 8);
    int swz = (l16 >> 1) & 3;

    auto stage = [&](int buf, int k0) {
#pragma unroll
        for (int c = 0; c < 4; c++) {
            int q = wave * 4 + c;
            int ch = q & 7;
            int r = ch * 16 + r_ld;
            const __hip_bfloat16* gp;
            short* lp;
            if (q < 8) { gp = Abf + ((size_t)(row0 + r) << 8) + k0 + koff; lp = &As[buf][ch * 512]; }
            else       { gp = Bt  + ((size_t)(col0 + r) << 8) + k0 + koff; lp = &Bs[buf][ch * 512]; }
            __builtin_amdgcn_global_load_lds(
                (const __attribute__((address_space(1))) unsigned int*)(uintptr_t)gp,
                (__attribute__((address_space(3))) unsigned int*)(uintptr_t)lp,
                16, 0, 0);
        }
    };

    stage(0, 0);
    stage(1, 32);
    for (int kk = 0; kk < 8; kk++) {
        int cur = kk % 3;
        if (kk + 2 < 8) {
            stage((kk + 2) % 3, (kk + 2) * 32);
            PIPE_WAIT_ENTER(8)
        } else if (kk + 1 < 8) {
            PIPE_WAIT_ENTER(4)
        } else {
            PIPE_WAIT_ENTER(0)
        }
        bf16x8 a[4], b[4];
#pragma unroll
        for (int i = 0; i < 4; i++)
            a[i] = *(const bf16x8*)&As[cur][(wm * 64 + i * 16 + l16) * 32 + ((quad ^ swz) << 3)];
#pragma unroll
        for (int j = 0; j < 4; j++)
            b[j] = *(const bf16x8*)&Bs[cur][(wn * 64 + j * 16 + l16) * 32 + ((quad ^ swz) << 3)];
#pragma unroll
        for (int i = 0; i < 4; i++)
#pragma unroll
            for (int j = 0; j < 4; j++)
                acc[i][j] = __builtin_amdgcn_mfma_f32_16x16x32_bf16(a[i], b[j], acc[i][j], 0, 0, 0);
        PIPE_EXIT()
    }

#pragma unroll
    for (int i = 0; i < 4; i++) {
        int gm0 = row0 + wm * 64 + i * 16 + quad * 4;
#pragma unroll
        for (int r = 0; r < 4; r++) {
            int gm = gm0 + r;
            if (gm < N_) {
#pragma unroll
                for (int j = 0; j < 4; j++) {
                    int col = col0 + wn * 64 + l16 + j * 16;
                    float v = acc[i][j][r] + (ob ? 0.f : bhh[col]);
                    C[(size_t)gm * ldc + col] = v;
                }
            }
        }
    }
}

// V = Abf(2048x256) @ Bt^T(32768x256) -> fp8 e4m3 (x64 scale).
// Output layout permuted for coalesced per-row reads: V8[n][k16][o][b].
__global__ __launch_bounds__(256, 3) void k_gemm_V_mfma(const __hip_bfloat16* __restrict__ A,
                                                        const __hip_bfloat16* __restrict__ Bt,
                                                        unsigned char* __restrict__ V8) {
    __shared__ __align__(16) short As[3][4096];
    __shared__ __align__(16) short Bs[3][4096];
    short* Ps = &As[0][0];               // epilogue alias: 32 x 136 shorts = 8704 B
    int t = threadIdx.x;
    int lane = t & 63, wave = t >> 6;
    int wm = wave >> 1, wn = wave & 1;
    int quad = lane >> 4, l16 = lane & 15;
    int row0 = blockIdx.y * 128, col0 = blockIdx.x * 128;

    f32x4 acc[4][4] = {};
    int r_ld = (lane >> 2);
    int koff = (((lane & 3) ^ ((lane >> 3) & 3)) * 8);  // swizzled 16B slot
    int swz = (l16 >> 1) & 3;
    int obase = (int)blockIdx.x * 8;                    // o = (obase+ch)&255
    int kb = ((int)blockIdx.x >> 5) * 16;               // k16*16

    auto stage = [&](int buf, int k0) {
#pragma unroll
        for (int c = 0; c < 4; c++) {
            int q = wave * 4 + c;
            int ch = q & 7;
            const __hip_bfloat16* gp;
            short* lp;
            if (q < 8) {
                gp = A + ((size_t)(row0 + ch * 16 + r_ld) << 8) + k0 + koff;
                lp = &As[buf][ch * 512];
            } else {
                int nv = ((obase + ch) & 255) * 128 + kb + r_ld;   // f -> nv remap
                gp = Bt + ((size_t)nv << 8) + k0 + koff;
                lp = &Bs[buf][ch * 512];
            }
            __builtin_amdgcn_global_load_lds(
                (const __attribute__((address_space(1))) unsigned int*)(uintptr_t)gp,
                (__attribute__((address_space(3))) unsigned int*)(uintptr_t)lp,
                16, 0, 0);
        }
    };

    stage(0, 0);
    stage(1, 32);
    for (int kk = 0; kk < 8; kk++) {
        int cur = kk % 3;
        if (kk + 2 < 8) {
            stage((kk + 2) % 3, (kk + 2) * 32);
            PIPE_WAIT_ENTER(8)
        } else if (kk + 1 < 8) {
            PIPE_WAIT_ENTER(4)
        } else {
            PIPE_WAIT_ENTER(0)
        }
        bf16x8 a[4], b[4];
#pragma unroll
        for (int i = 0; i < 4; i++)
            a[i] = *(const bf16x8*)&As[cur][(wm * 64 + i * 16 + l16) * 32 + ((quad ^ swz) << 3)];
#pragma unroll
        for (int j = 0; j < 4; j++)
            b[j] = *(const bf16x8*)&Bs[cur][(wn * 64 + j * 16 + l16) * 32 + ((quad ^ swz) << 3)];
#pragma unroll
        for (int i = 0; i < 4; i++)
#pragma unroll
            for (int j = 0; j < 4; j++)
                acc[i][j] = __builtin_amdgcn_mfma_f32_16x16x32_bf16(a[i], b[j], acc[i][j], 0, 0, 0);
        PIPE_EXIT()
    }

    // 4-pass epilogue: stage 32 scaled-bf16 rows in Ps, convert+store coalesced uint4.
#pragma unroll
    for (int pp = 0; pp < 4; pp++) {
        if (wm == (pp >> 1)) {
#pragma unroll
            for (int ii = 0; ii < 2; ii++) {
                const int i = (pp & 1) * 2 + ii;       // compile-time acc index
                int lr = ii * 16 + quad * 4;           // local row in [0,32)
#pragma unroll
                for (int r = 0; r < 4; r++) {
#pragma unroll
                    for (int j = 0; j < 4; j++) {
                        int col = wn * 64 + j * 16 + l16;
                        Ps[(lr + r) * 136 + col] = bfbits(acc[i][j][r] * VSCALE);
                    }
                }
            }
        }
        __syncthreads();
        {
            int row = t >> 3;            // 0..31
            int col = (t & 7) * 16;      // 0..112 step 16
            int gm = row0 + pp * 32 + row;
            if (gm < N_) {
                uint4 ua = *(const uint4*)&Ps[row * 136 + col];
                uint4 ub = *(const uint4*)&Ps[row * 136 + col + 8];
                unsigned p0 = __builtin_amdgcn_cvt_pk_fp8_f32(bf_lo(ua.x), bf_hi(ua.x), 0, false);
                p0 = __builtin_amdgcn_cvt_pk_fp8_f32(bf_lo(ua.y), bf_hi(ua.y), p0, true);
                unsigned p1 = __builtin_amdgcn_cvt_pk_fp8_f32(bf_lo(ua.z), bf_hi(ua.z), 0, false);
                p1 = __builtin_amdgcn_cvt_pk_fp8_f32(bf_lo(ua.w), bf_hi(ua.w), p1, true);
                unsigned p2 = __builtin_amdgcn_cvt_pk_fp8_f32(bf_lo(ub.x), bf_hi(ub.x), 0, false);
                p2 = __builtin_amdgcn_cvt_pk_fp8_f32(bf_lo(ub.y), bf_hi(ub.y), p2, true);
                unsigned p3 = __builtin_amdgcn_cvt_pk_fp8_f32(bf_lo(ub.z), bf_hi(ub.z), 0, false);
                p3 = __builtin_amdgcn_cvt_pk_fp8_f32(bf_lo(ub.w), bf_hi(ub.w), p3, true);
                uint4 o4;
                o4.x = p0; o4.y = p1; o4.z = p2; o4.w = p3;
                *(uint4*)(V8 + (size_t)gm * NV_ + col0 + col) = o4;
            }
        }
        __syncthreads();
    }
}

// Tail GEMM with packed B (384x512): cols 0..255 -> relu->o1bf; cols 256..383 -> h1.
__global__ __launch_bounds__(256, 3) void k_gemm_tail(const __hip_bfloat16* __restrict__ A,
                                                      const __hip_bfloat16* __restrict__ Bpk,
                                                      const float* __restrict__ b1,
                                                      const float* __restrict__ b2,
                                                      __hip_bfloat16* __restrict__ o1bf,
                                                      float* __restrict__ h1) {
    __shared__ __align__(16) short As[3][4096];
    __shared__ __align__(16) short Bs[3][4096];
    int t = threadIdx.x;
    int lane = t & 63, wave = t >> 6;
    int wm = wave >> 1, wn = wave & 1;
    int quad = lane >> 4, l16 = lane & 15;
    int row0 = blockIdx.y * 128, col0 = blockIdx.x * 128;

    f32x4 acc[4][4] = {};
    int r_ld = (lane >> 2);
    int koff = (((lane & 3) ^ ((lane >> 3) & 3)) * 8);
    int swz = (l16 >> 1) & 3;

    auto stage = [&](int buf, int k0) {
#pragma unroll
        for (int c = 0; c < 4; c++) {
            int q = wave * 4 + c;
            int ch = q & 7;
            int r = ch * 16 + r_ld;
            const __hip_bfloat16* gp;
            short* lp;
            if (q < 8) { gp = A   + (size_t)(row0 + r) * 512 + k0 + koff; lp = &As[buf][ch * 512]; }
            else       { gp = Bpk + (size_t)(col0 + r) * 512 + k0 + koff; lp = &Bs[buf][ch * 512]; }
            __builtin_amdgcn_global_load_lds(
                (const __attribute__((address_space(1))) unsigned int*)(uintptr_t)gp,
                (__attribute__((address_space(3))) unsigned int*)(uintptr_t)lp,
                16, 0, 0);
        }
    };

    stage(0, 0);
    stage(1, 32);
    for (int kk = 0; kk < 16; kk++) {
        int cur = kk % 3;
        if (kk + 2 < 16) {
            stage((kk + 2) % 3, (kk + 2) * 32);
            PIPE_WAIT_ENTER(8)
        } else if (kk + 1 < 16) {
            PIPE_WAIT_ENTER(4)
        } else {
            PIPE_WAIT_ENTER(0)
        }
        bf16x8 a[4], b[4];
#pragma unroll
        for (int i = 0; i < 4; i++)
            a[i] = *(const bf16x8*)&As[cur][(wm * 64 + i * 16 + l16) * 32 + ((quad ^ swz) << 3)];
#pragma unroll
        for (int j = 0; j < 4; j++)
            b[j] = *(const bf16x8*)&Bs[cur][(wn * 64 + j * 16 + l16) * 32 + ((quad ^ swz) << 3)];
#pragma unroll
        for (int i = 0; i < 4; i++)
#pragma unroll
            for (int j = 0; j < 4; j++)
                acc[i][j] = __builtin_amdgcn_mfma_f32_16x16x32_bf16(a[i], b[j], acc[i][j], 0, 0, 0);
        PIPE_EXIT()
    }

#pragma unroll
    for (int i = 0; i < 4; i++) {
        int gm0 = row0 + wm * 64 + i * 16 + quad * 4;
#pragma unroll
        for (int r = 0; r < 4; r++) {
            int gm = gm0 + r;
#pragma unroll
            for (int j = 0; j < 4; j++) {
                int col = col0 + wn * 64 + l16 + j * 16;
                float v = acc[i][j][r];
                if (col < 256) {
                    v = fmaxf(v + b1[col], 0.f);
                    o1bf[(size_t)gm * H_ + col] = __float2bfloat16(v);
                } else {
                    h1[(size_t)gm * 128 + (col - 256)] = v + b2[col - 256];
                }
            }
        }
    }
}

// Row-CSR message pass: one block per source row r; V[r] read ONCE into registers,
// then every outgoing edge served from regs + he in LDS.
// V8 layout [n][k16][o][16]: thread o's chunk for k-group q is at q*4096 + o*16.
__global__ void k_msg_row(const int* __restrict__ ei, const int* __restrict__ rowptr,
                          const int* __restrict__ eord, const float* __restrict__ he,
                          const unsigned char* __restrict__ V8, const float* __restrict__ outb,
                          float* __restrict__ agg) {
    int r = blockIdx.x, o = threadIdx.x;
    int s = rowptr[r];
    int eN = rowptr[r + 1] - s;
    if (eN == 0) return;
    __shared__ float hs[16][KH_];
    __shared__ int ecol[16];
    __shared__ int eidv[16];
    uint4 v[8];
    const unsigned char* vbase = V8 + (size_t)r * NV_ + o * 16;
#pragma unroll
    for (int q = 0; q < 8; q++) v[q] = *(const uint4*)(vbase + (size_t)q * 4096);
    float outb_ro = outb[(size_t)r * H_ + o];

    for (int c0 = 0; c0 < eN; c0 += 16) {
        int nc = min(16, eN - c0);
        if (o < nc) {
            int e = eord[s + c0 + o];
            eidv[o] = e;
            ecol[o] = ei[E_ + e];
        }
        __syncthreads();
        for (int idx = o; idx < nc * KH_; idx += 256) {
            int ie = idx >> 7, k = idx & 127;
            hs[ie][k] = he[eidv[ie] * KH_ + k] * VSCALE_INV;
        }
        __syncthreads();
        for (int ie = 0; ie < nc; ie++) {
            float acc = outb_ro;
            const float* hp0 = hs[ie];
#pragma unroll
            for (int q = 0; q < 8; q++) {
                uint4 u = v[q];
                const float* hp = hp0 + q * 16;
                f32x2 f;
                f = __builtin_amdgcn_cvt_pk_f32_fp8(u.x, false); acc += hp[0]  * f.x + hp[1]  * f.y;
                f = __builtin_amdgcn_cvt_pk_f32_fp8(u.x, true);  acc += hp[2]  * f.x + hp[3]  * f.y;
                f = __builtin_amdgcn_cvt_pk_f32_fp8(u.y, false); acc += hp[4]  * f.x + hp[5]  * f.y;
                f = __builtin_amdgcn_cvt_pk_f32_fp8(u.y, true);  acc += hp[6]  * f.x + hp[7]  * f.y;
                f = __builtin_amdgcn_cvt_pk_f32_fp8(u.z, false); acc += hp[8]  * f.x + hp[9]  * f.y;
                f = __builtin_amdgcn_cvt_pk_f32_fp8(u.z, true);  acc += hp[10] * f.x + hp[11] * f.y;
                f = __builtin_amdgcn_cvt_pk_f32_fp8(u.w, false); acc += hp[12] * f.x + hp[13] * f.y;
                f = __builtin_amdgcn_cvt_pk_f32_fp8(u.w, true);  acc += hp[14] * f.x + hp[15] * f.y;
            }
            atomicAdd(&agg[(size_t)ecol[ie] * H_ + o], acc);
        }
        __syncthreads();
    }
}

// Mbf = bf16(relu(agg / max(counts,1) + conv_b))
__global__ void k_m(const float* __restrict__ agg, const float* __restrict__ counts,
                    const float* __restrict__ conv_b, __hip_bfloat16* __restrict__ Mbf) {
    int i = blockIdx.x * blockDim.x + threadIdx.x;
    if (i >= N_ * H_) return;
    int n = i >> 8, o = i & 255;
    float c = fmaxf(counts[n], 1.0f);
    Mbf[i] = __float2bfloat16(fmaxf(agg[i] / c + conv_b[o], 0.f));
}

// GRU pointwise; also refreshes Abf = bf16(h)
__global__ void k_gru_update(const float* __restrict__ gi, const float* __restrict__ gh,
                             float* __restrict__ h, __hip_bfloat16* __restrict__ Abf) {
    int i = blockIdx.x * blockDim.x + threadIdx.x;
    if (i >= N_ * H_) return;
    int n = i >> 8, j = i & 255;
    const float* gip = gi + (size_t)n * NG_;
    const float* ghp = gh + (size_t)n * NG_;
    float r = 1.f / (1.f + expf(-(gip[j] + ghp[j])));
    float z = 1.f / (1.f + expf(-(gip[H_ + j] + ghp[H_ + j])));
    float nn = tanhf(gip[2 * H_ + j] + r * ghp[2 * H_ + j]);
    float hv = (1.f - z) * nn + z * h[i];
    h[i] = hv;
    Abf[i] = __float2bfloat16(hv);
}

// batchnorm stats over E rows, per column j   grid 128, block 256
__global__ void k_bnstats(const float* __restrict__ h1, float* __restrict__ mu,
                          float* __restrict__ rsig) {
    int j = blockIdx.x, t = threadIdx.x;
    float s = 0.f, ss = 0.f;
    for (int e = t; e < E_; e += 256) {
        float v = h1[(size_t)e * 128 + j];
        s += v;
        ss += v * v;
    }
    __shared__ float rs[256], rss[256];
    rs[t] = s; rss[t] = ss;
    __syncthreads();
    for (int off = 128; off > 0; off >>= 1) {
        if (t < off) { rs[t] += rs[t + off]; rss[t] += rss[t + off]; }
        __syncthreads();
    }
    if (t == 0) {
        float m_ = rs[0] / E_;
        float v_ = rss[0] / E_ - m_ * m_;
        mu[j] = m_;
        rsig[j] = rsqrtf(v_ + 1e-5f);
    }
}

// precs[e] = relu(bn(h1[e])) . l6_W2 + b
__global__ void k_precs(const float* __restrict__ h1, const float* __restrict__ mu,
                        const float* __restrict__ rsig, const float* __restrict__ g,
                        const float* __restrict__ bb, const float* __restrict__ W2,
                        const float* __restrict__ b2, float* __restrict__ out) {
    int e = blockIdx.x * blockDim.x + threadIdx.x;
    if (e >= E_) return;
    float acc = b2[0];
#pragma unroll 4
    for (int j = 0; j < 128; j++) {
        float v = (h1[(size_t)e * 128 + j] - mu[j]) * rsig[j] * g[j] + bb[j];
        acc += fmaxf(v, 0.f) * W2[j];
    }
    out[(size_t)E_ * 242 + e] = acc;
}

extern "C" void kernel_launch(void* const* d_in, const int* in_sizes, int n_in,
                              void* d_out, int out_size, void* d_ws, size_t ws_size,
                              hipStream_t stream) {
    const int*   x        = (const int*)  d_in[0];
    const float* pos      = (const float*)d_in[1];
    const int*   ei       = (const int*)  d_in[2];
    const float* edge_atr = (const float*)d_in[3];
    const float* emb      = (const float*)d_in[4];
    const float* lin0_W   = (const float*)d_in[5];
    const float* lin0_b   = (const float*)d_in[6];
    const float* mlp1_W   = (const float*)d_in[7];
    const float* mlp1_b   = (const float*)d_in[8];
    const float* mlp2_W   = (const float*)d_in[9];
    const float* mlp2_b   = (const float*)d_in[10];
    const float* conv_b   = (const float*)d_in[11];
    const float* gru_Wih  = (const float*)d_in[12];
    const float* gru_Whh  = (const float*)d_in[13];
    const float* gru_bih  = (const float*)d_in[14];
    const float* gru_bhh  = (const float*)d_in[15];
    const float* lin1_W   = (const float*)d_in[16];
    const float* lin1_b   = (const float*)d_in[17];
    const float* lin2_W   = (const float*)d_in[18];
    const float* lin2_b   = (const float*)d_in[19];
    const float* l6_W1    = (const float*)d_in[20];
    const float* l6_b1    = (const float*)d_in[21];
    const float* bn_g     = (const float*)d_in[22];
    const float* bn_b     = (const float*)d_in[23];
    const float* l6_W2    = (const float*)d_in[24];
    const float* l6_b2    = (const float*)d_in[25];
    float* out = (float*)d_out;

    // workspace layout
    char* w = (char*)d_ws;
    size_t off = 0;
    auto alloc = [&](size_t bytes) -> void* {
        void* p = w + off;
        off = (off + bytes + 255) & ~(size_t)255;
        return p;
    };
    float* hbuf   = (float*)alloc((size_t)N_ * H_ * 4);
    float* aggm   = (float*)alloc((size_t)N_ * H_ * 4);
    float* outb   = (float*)alloc((size_t)N_ * H_ * 4);
    float* he     = (float*)alloc((size_t)E_ * KH_ * 4);
    float* gi     = (float*)alloc((size_t)N_ * NG_ * 4);
    float* gh     = (float*)alloc((size_t)N_ * NG_ * 4);
    float* h1     = (float*)alloc((size_t)E_ * 128 * 4);
    float* counts = (float*)alloc((size_t)N_ * 4);
    float* mu     = (float*)alloc(128 * 4);
    float* rsig   = (float*)alloc(128 * 4);
    int*   degwc  = (int*)  alloc((size_t)2 * N_ * 4);   // deg | wcur
    int*   deg    = degwc;
    int*   wcur   = degwc + N_;
    int*   rowptr = (int*)  alloc((size_t)(N_ + 1) * 4);
    int*   eord   = (int*)  alloc((size_t)E_ * 4);
    unsigned char* V8      = (unsigned char*)alloc((size_t)N_ * NV_);          // 65.5 MB fp8
    __hip_bfloat16* Abf    = (__hip_bfloat16*)alloc((size_t)MPAD_ * H_ * 2);
    __hip_bfloat16* Mbf    = (__hip_bfloat16*)alloc((size_t)MPAD_ * H_ * 2);
    __hip_bfloat16* Bt     = (__hip_bfloat16*)alloc((size_t)NV_ * H_ * 2);     // 16.8 MB
    __hip_bfloat16* WihB   = (__hip_bfloat16*)alloc((size_t)NG_ * H_ * 2);
    __hip_bfloat16* WhhB   = (__hip_bfloat16*)alloc((size_t)NG_ * H_ * 2);
    __hip_bfloat16* Bpk    = (__hip_bfloat16*)alloc((size_t)384 * 512 * 2);
    __hip_bfloat16* lin2Wb = (__hip_bfloat16*)alloc((size_t)H_ * H_ * 2);
    __hip_bfloat16* BtB    = (__hip_bfloat16*)alloc((size_t)H_ * H_ * 2);
    __hip_bfloat16* Cbf    = (__hip_bfloat16*)alloc((size_t)E_ * 2 * H_ * 2);
    __hip_bfloat16* o1bf   = (__hip_bfloat16*)alloc((size_t)E_ * H_ * 2);

    k_lin0<<<MPAD_, 256, 0, stream>>>(x, pos, emb, lin0_W, lin0_b, hbuf, Abf);
    k_he<<<E_, 128, 0, stream>>>(edge_atr, mlp1_W, mlp1_b, he);
    hipMemsetAsync(counts, 0, (size_t)N_ * 4, stream);
    hipMemsetAsync(degwc, 0, (size_t)2 * N_ * 4, stream);
    k_counts<<<(E_ + 255) / 256, 256, 0, stream>>>(ei, counts, deg);
    k_scan<<<1, 256, 0, stream>>>(deg, rowptr);
    k_fill<<<(E_ + 255) / 256, 256, 0, stream>>>(ei, rowptr, wcur, eord);
    k_trans_bt<<<dim3(NV_ / 64, H_ / 32), 256, 0, stream>>>(mlp2_W, Bt);
    k_prep_w<<<768, 256, 0, stream>>>(gru_Wih, gru_Whh, lin1_W, l6_W1, lin2_W, mlp2_b,
                                      WihB, WhhB, Bpk, lin2Wb, BtB);

    for (int it = 0; it < 3; it++) {
        // gh = Abf @ Whh^T + bhh  AND  outb = Abf @ BtB^T (both off critical path of msg)
        k_gemm_pair<<<dim3(8, MPAD_ / 128), 256, 0, stream>>>(Abf, WhhB, BtB,
                                                              gru_bhh, gh, outb);
        dim3 gv(NV_ / 128, MPAD_ / 128);
        k_gemm_V_mfma<<<gv, 256, 0, stream>>>(Abf, Bt, V8);
        hipMemsetAsync(aggm, 0, (size_t)N_ * H_ * 4, stream);
        k_msg_row<<<N_, 256, 0, stream>>>(ei, rowptr, eord, he, V8, outb, aggm);
        k_m<<<(N_ * H_ + 255) / 256, 256, 0, stream>>>(aggm, counts, conv_b, Mbf);
        // gi = Mbf @ Wih^T + bih
        k_gemm_nt<256, false, false><<<dim3(6, MPAD_ / 128), 256, 0, stream>>>(
            Mbf, WihB, gi, nullptr, gru_bih, NG_, NG_, N_);
        k_gru_update<<<(N_ * H_ + 255) / 256, 256, 0, stream>>>(gi, gh, hbuf, Abf);
    }

    k_concat<<<E_, 256, 0, stream>>>(ei, hbuf, Cbf);
    k_gemm_tail<<<dim3(3, E_ / 128), 256, 0, stream>>>(Cbf, Bpk, lin1_b, l6_b1, o1bf, h1);
    k_gemm_nt<256, false, false><<<dim3(2, E_ / 128), 256, 0, stream>>>(
        o1bf, lin2Wb, out, nullptr, lin2_b, 242, 242, E_);
    k_bnstats<<<128, 256, 0, stream>>>(h1, mu, rsig);
    k_precs<<<(E_ + 255) / 256, 256, 0, stream>>>(h1, mu, rsig, bn_g, bn_b, l6_W2, l6_b2, out);
}

// Round 4
// 465.091 us; speedup vs baseline: 1.3909x; 1.3909x over previous
//
#include <hip/hip_runtime.h>
#include <hip/hip_bf16.h>

// Problem constants (fixed by the reference)
constexpr int N_ = 2000;   // nodes
constexpr int E_ = 4096;   // edges
constexpr int H_ = 256;    // hidden
constexpr int KH_ = 128;   // he dim (mlp1 out)
constexpr int NV_ = H_ * KH_; // 32768, V row length — fp8 bytes
constexpr int MPAD_ = 2048;   // padded M for node-side MFMA GEMMs
constexpr int NG_ = 768;      // GRU gate width (3*H)
constexpr float VSCALE = 64.f;     // fp8 scale for V (avoids e4m3 subnormals)
constexpr float VSCALE_INV = 1.f / 64.f;

typedef short bf16x8 __attribute__((ext_vector_type(8)));
typedef float f32x4  __attribute__((ext_vector_type(4)));
typedef float f32x2  __attribute__((ext_vector_type(2)));

__device__ __forceinline__ float bf_lo(unsigned u) { return __uint_as_float(u << 16); }
__device__ __forceinline__ float bf_hi(unsigned u) { return __uint_as_float(u & 0xffff0000u); }
__device__ __forceinline__ short bfbits(float f) {
    __hip_bfloat16 b = __float2bfloat16(f);
    return *(short*)&b;
}

// ---- pipeline sync helpers (T4: counted vmcnt across raw barrier), depth-2 ----
#define PIPE_WAIT_ENTER(N_OUTST)                                   \
    asm volatile("s_waitcnt vmcnt(" #N_OUTST ")" ::: "memory");    \
    __builtin_amdgcn_s_barrier();                                  \
    asm volatile("" ::: "memory");                                 \
    __builtin_amdgcn_sched_barrier(0);

#define PIPE_EXIT()                                                \
    __builtin_amdgcn_sched_barrier(0);                             \
    asm volatile("" ::: "memory");                                 \
    __builtin_amdgcn_s_barrier();

// out = relu([emb[x], pos] @ lin0_W.T + b); also emits Abf (bf16, zero-padded rows).
__global__ void k_lin0(const int* __restrict__ x, const float* __restrict__ pos,
                       const float* __restrict__ emb, const float* __restrict__ W,
                       const float* __restrict__ b, float* __restrict__ out,
                       __hip_bfloat16* __restrict__ Abf) {
    int n = blockIdx.x, t = threadIdx.x;
    if (n >= N_) { Abf[(size_t)n * H_ + t] = __float2bfloat16(0.f); return; }
    __shared__ float in_p[8];
    if (t < 5) in_p[t] = emb[x[n] * 5 + t];
    else if (t < 8) in_p[t] = pos[n * 3 + (t - 5)];
    __syncthreads();
    float acc = b[t];
#pragma unroll
    for (int i = 0; i < 8; i++) acc += in_p[i] * W[t * 8 + i];
    float v = fmaxf(acc, 0.f);
    out[n * H_ + t] = v;
    Abf[(size_t)n * H_ + t] = __float2bfloat16(v);
}

// he = relu(edge_atr @ mlp1_W.T + b)   grid E, block 128
__global__ void k_he(const float* __restrict__ ea, const float* __restrict__ W,
                     const float* __restrict__ b, float* __restrict__ he) {
    int e = blockIdx.x, t = threadIdx.x;
    __shared__ float a[5];
    if (t < 5) a[t] = ea[e * 5 + t];
    __syncthreads();
    float acc = b[t];
#pragma unroll
    for (int i = 0; i < 5; i++) acc += a[i] * W[t * 5 + i];
    he[e * KH_ + t] = fmaxf(acc, 0.f);
}

__global__ void k_counts(const int* __restrict__ ei, float* __restrict__ counts) {
    int e = blockIdx.x * blockDim.x + threadIdx.x;
    if (e < E_) atomicAdd(&counts[ei[E_ + e]], 1.0f);
}

// Bt[nv][h] = mlp2_W[h*32768 + nv] as bf16 (transpose+convert), once per launch.
// float4 loads, short4 stores.
__global__ void k_trans_bt(const float* __restrict__ W, __hip_bfloat16* __restrict__ Bt) {
    __shared__ float tile[32][68];   // 68: 16B-aligned rows, bank-shifted
    int t = threadIdx.x;
    int n0 = blockIdx.x * 64, k0 = blockIdx.y * 32;
#pragma unroll
    for (int i = 0; i < 2; i++) {
        int idx = t + i * 256;                 // 0..511
        int kk = idx >> 4, nn = (idx & 15) * 4;
        float4 f = *(const float4*)&W[(size_t)(k0 + kk) * NV_ + n0 + nn];
        *(float4*)&tile[kk][nn] = f;
    }
    __syncthreads();
#pragma unroll
    for (int i = 0; i < 2; i++) {
        int idx = t + i * 256;                 // 0..511
        int nn = idx >> 3, k4 = (idx & 7) * 4;
        short4 s;
        s.x = bfbits(tile[k4 + 0][nn]);
        s.y = bfbits(tile[k4 + 1][nn]);
        s.z = bfbits(tile[k4 + 2][nn]);
        s.w = bfbits(tile[k4 + 3][nn]);
        *(short4*)&Bt[(size_t)(n0 + nn) * H_ + k0 + k4] = s;
    }
}

// One-time weight preps (bf16 converts + packed tail B + lin2 pad + mlp2_b transpose).
__global__ void k_prep_w(const float* __restrict__ Wih, const float* __restrict__ Whh,
                         const float* __restrict__ lin1W, const float* __restrict__ l6W1,
                         const float* __restrict__ lin2W, const float* __restrict__ b2,
                         __hip_bfloat16* __restrict__ WihB, __hip_bfloat16* __restrict__ WhhB,
                         __hip_bfloat16* __restrict__ Bpk,
                         __hip_bfloat16* __restrict__ lin2Wb, __hip_bfloat16* __restrict__ BtB) {
    int i = blockIdx.x * 256 + threadIdx.x;     // i < 196608
    if (i < NG_ * H_) {
        WihB[i] = __float2bfloat16(Wih[i]);
        WhhB[i] = __float2bfloat16(Whh[i]);
    }
    Bpk[i] = __float2bfloat16(i < 256 * 512 ? lin1W[i] : l6W1[i - 256 * 512]);
    if (i < 128 * 2 * H_) {
        int r = i >> 8, k = i & 255;
        lin2Wb[i] = __float2bfloat16(r < 242 ? lin2W[r * H_ + k] : 0.f);
        int o = i >> 8, h = i & 255;
        BtB[o * H_ + h] = __float2bfloat16(b2[h * H_ + o]);
    }
}

// Cbf[e] = bf16([h[row[e]], h[col[e]]])   grid E, block 256
__global__ void k_concat(const int* __restrict__ ei, const float* __restrict__ h,
                         __hip_bfloat16* __restrict__ Cbf) {
    int e = blockIdx.x, t = threadIdx.x;
    int r = ei[e], c = ei[E_ + e];
    Cbf[(size_t)e * 512 + t]       = __float2bfloat16(h[(size_t)r * H_ + t]);
    Cbf[(size_t)e * 512 + 256 + t] = __float2bfloat16(h[(size_t)c * H_ + t]);
}

// Generic MFMA GEMM: C(MxN) = A(MxKD bf16) @ Bt(NxKD bf16)^T [+bias][relu].
// Depth-2 pipeline (counted vmcnt(4) across raw barrier).
template <int KD, bool RELU, bool OUT_BF16>
__global__ __launch_bounds__(256, 3) void k_gemm_nt(const __hip_bfloat16* __restrict__ A,
                                                    const __hip_bfloat16* __restrict__ Bt,
                                                    float* __restrict__ Cf,
                                                    __hip_bfloat16* __restrict__ Cb,
                                                    const float* __restrict__ bias,
                                                    int ldc, int ncols, int mvalid) {
    __shared__ __align__(16) short As[2][4096];
    __shared__ __align__(16) short Bs[2][4096];
    int t = threadIdx.x;
    int lane = t & 63, wave = t >> 6;
    int wm = wave >> 1, wn = wave & 1;
    int quad = lane >> 4, l16 = lane & 15;
    int row0 = blockIdx.y * 128, col0 = blockIdx.x * 128;

    f32x4 acc[4][4] = {};
    int r_ld = (lane >> 2);
    int koff = (((lane & 3) ^ ((lane >> 3) & 3)) * 8);  // swizzled 16B slot
    int swz = (l16 >> 1) & 3;                           // read-side slot XOR
    constexpr int NST = KD / 32;

    auto stage = [&](int buf, int k0) {
#pragma unroll
        for (int c = 0; c < 4; c++) {
            int q = wave * 4 + c;
            int ch = q & 7;
            int r = ch * 16 + r_ld;
            const __hip_bfloat16* gp;
            short* lp;
            if (q < 8) { gp = A  + (size_t)(row0 + r) * KD + k0 + koff; lp = &As[buf][ch * 512]; }
            else       { gp = Bt + (size_t)(col0 + r) * KD + k0 + koff; lp = &Bs[buf][ch * 512]; }
            __builtin_amdgcn_global_load_lds(
                (const __attribute__((address_space(1))) unsigned int*)(uintptr_t)gp,
                (__attribute__((address_space(3))) unsigned int*)(uintptr_t)lp,
                16, 0, 0);
        }
    };

    stage(0, 0);
    for (int kk = 0; kk < NST; kk++) {
        int cur = kk & 1;
        if (kk + 1 < NST) {
            stage(cur ^ 1, (kk + 1) * 32);
            PIPE_WAIT_ENTER(4)
        } else {
            PIPE_WAIT_ENTER(0)
        }
        bf16x8 a[4], b[4];
#pragma unroll
        for (int i = 0; i < 4; i++)
            a[i] = *(const bf16x8*)&As[cur][(wm * 64 + i * 16 + l16) * 32 + ((quad ^ swz) << 3)];
#pragma unroll
        for (int j = 0; j < 4; j++)
            b[j] = *(const bf16x8*)&Bs[cur][(wn * 64 + j * 16 + l16) * 32 + ((quad ^ swz) << 3)];
#pragma unroll
        for (int i = 0; i < 4; i++)
#pragma unroll
            for (int j = 0; j < 4; j++)
                acc[i][j] = __builtin_amdgcn_mfma_f32_16x16x32_bf16(a[i], b[j], acc[i][j], 0, 0, 0);
        PIPE_EXIT()
    }

#pragma unroll
    for (int i = 0; i < 4; i++) {
        int gm0 = row0 + wm * 64 + i * 16 + quad * 4;
#pragma unroll
        for (int r = 0; r < 4; r++) {
            int gm = gm0 + r;
            if (gm < mvalid) {
#pragma unroll
                for (int j = 0; j < 4; j++) {
                    int col = col0 + wn * 64 + l16 + j * 16;
                    if (col < ncols) {
                        float v = acc[i][j][r];
                        if (bias) v += bias[col];
                        if (RELU) v = fmaxf(v, 0.f);
                        if (OUT_BF16) Cb[(size_t)gm * ldc + col] = __float2bfloat16(v);
                        else          Cf[(size_t)gm * ldc + col] = v;
                    }
                }
            }
        }
    }
}

// Fused per-iteration GEMM launch (one grid, block-uniform branch):
//   blocks [0,128):    pair part — pbx=bid&7, pby=bid>>3
//       pbx 0..5: gh = Abf @ WhhB^T + bhh  (ldc 768)
//       pbx 6..7: outb = Abf @ BtB^T       (ldc 256)
//   blocks [128,4224): V part — vb=bid-128, bx=vb&255, by=vb>>8
//       V = Abf @ Bt^T -> fp8 e4m3 (x64), permuted layout V8[n][k16][o][16]
__global__ __launch_bounds__(256, 3) void k_gemm_VP(const __hip_bfloat16* __restrict__ Abf,
                                                    const __hip_bfloat16* __restrict__ Bt,
                                                    const __hip_bfloat16* __restrict__ WhhB,
                                                    const __hip_bfloat16* __restrict__ BtB,
                                                    const float* __restrict__ bhh,
                                                    float* __restrict__ gh,
                                                    float* __restrict__ outb,
                                                    unsigned char* __restrict__ V8) {
    __shared__ __align__(16) short As[2][4096];
    __shared__ __align__(16) short Bs[2][4096];
    int bid = blockIdx.x;
    int t = threadIdx.x;
    int lane = t & 63, wave = t >> 6;
    int wm = wave >> 1, wn = wave & 1;
    int quad = lane >> 4, l16 = lane & 15;
    int r_ld = (lane >> 2);
    int koff = (((lane & 3) ^ ((lane >> 3) & 3)) * 8);
    int swz = (l16 >> 1) & 3;

    if (bid < 128) {
        // ---------------- pair part ----------------
        int pbx = bid & 7, pby = bid >> 3;
        bool ob = (pbx >= 6);
        const __hip_bfloat16* Bp = ob ? BtB : WhhB;
        int col0 = ob ? (pbx - 6) * 128 : pbx * 128;
        int ldc = ob ? H_ : NG_;
        float* C = ob ? outb : gh;
        int row0 = pby * 128;

        f32x4 acc[4][4] = {};
        auto stage = [&](int buf, int k0) {
#pragma unroll
            for (int c = 0; c < 4; c++) {
                int q = wave * 4 + c;
                int ch = q & 7;
                int r = ch * 16 + r_ld;
                const __hip_bfloat16* gp;
                short* lp;
                if (q < 8) { gp = Abf + ((size_t)(row0 + r) << 8) + k0 + koff; lp = &As[buf][ch * 512]; }
                else       { gp = Bp  + ((size_t)(col0 + r) << 8) + k0 + koff; lp = &Bs[buf][ch * 512]; }
                __builtin_amdgcn_global_load_lds(
                    (const __attribute__((address_space(1))) unsigned int*)(uintptr_t)gp,
                    (__attribute__((address_space(3))) unsigned int*)(uintptr_t)lp,
                    16, 0, 0);
            }
        };
        stage(0, 0);
        for (int kk = 0; kk < 8; kk++) {
            int cur = kk & 1;
            if (kk + 1 < 8) {
                stage(cur ^ 1, (kk + 1) * 32);
                PIPE_WAIT_ENTER(4)
            } else {
                PIPE_WAIT_ENTER(0)
            }
            bf16x8 a[4], b[4];
#pragma unroll
            for (int i = 0; i < 4; i++)
                a[i] = *(const bf16x8*)&As[cur][(wm * 64 + i * 16 + l16) * 32 + ((quad ^ swz) << 3)];
#pragma unroll
            for (int j = 0; j < 4; j++)
                b[j] = *(const bf16x8*)&Bs[cur][(wn * 64 + j * 16 + l16) * 32 + ((quad ^ swz) << 3)];
#pragma unroll
            for (int i = 0; i < 4; i++)
#pragma unroll
                for (int j = 0; j < 4; j++)
                    acc[i][j] = __builtin_amdgcn_mfma_f32_16x16x32_bf16(a[i], b[j], acc[i][j], 0, 0, 0);
            PIPE_EXIT()
        }
#pragma unroll
        for (int i = 0; i < 4; i++) {
            int gm0 = row0 + wm * 64 + i * 16 + quad * 4;
#pragma unroll
            for (int r = 0; r < 4; r++) {
                int gm = gm0 + r;
                if (gm < N_) {
#pragma unroll
                    for (int j = 0; j < 4; j++) {
                        int col = col0 + wn * 64 + l16 + j * 16;
                        float v = acc[i][j][r] + (ob ? 0.f : bhh[col]);
                        C[(size_t)gm * ldc + col] = v;
                    }
                }
            }
        }
        return;
    }

    // ---------------- V part ----------------
    int vb = bid - 128;
    int bx = vb & 255, by = vb >> 8;
    int row0 = by * 128, col0 = bx * 128;
    int obase = bx * 8;                    // o = (obase+ch)&255
    int kb = (bx >> 5) * 16;               // k16*16
    short* Ps = &As[0][0];                 // epilogue alias: 32 x 136 shorts

    f32x4 acc[4][4] = {};
    auto stage = [&](int buf, int k0) {
#pragma unroll
        for (int c = 0; c < 4; c++) {
            int q = wave * 4 + c;
            int ch = q & 7;
            const __hip_bfloat16* gp;
            short* lp;
            if (q < 8) {
                gp = Abf + ((size_t)(row0 + ch * 16 + r_ld) << 8) + k0 + koff;
                lp = &As[buf][ch * 512];
            } else {
                int nv = ((obase + ch) & 255) * 128 + kb + r_ld;   // f -> nv remap
                gp = Bt + ((size_t)nv << 8) + k0 + koff;
                lp = &Bs[buf][ch * 512];
            }
            __builtin_amdgcn_global_load_lds(
                (const __attribute__((address_space(1))) unsigned int*)(uintptr_t)gp,
                (__attribute__((address_space(3))) unsigned int*)(uintptr_t)lp,
                16, 0, 0);
        }
    };
    stage(0, 0);
    for (int kk = 0; kk < 8; kk++) {
        int cur = kk & 1;
        if (kk + 1 < 8) {
            stage(cur ^ 1, (kk + 1) * 32);
            PIPE_WAIT_ENTER(4)
        } else {
            PIPE_WAIT_ENTER(0)
        }
        bf16x8 a[4], b[4];
#pragma unroll
        for (int i = 0; i < 4; i++)
            a[i] = *(const bf16x8*)&As[cur][(wm * 64 + i * 16 + l16) * 32 + ((quad ^ swz) << 3)];
#pragma unroll
        for (int j = 0; j < 4; j++)
            b[j] = *(const bf16x8*)&Bs[cur][(wn * 64 + j * 16 + l16) * 32 + ((quad ^ swz) << 3)];
#pragma unroll
        for (int i = 0; i < 4; i++)
#pragma unroll
            for (int j = 0; j < 4; j++)
                acc[i][j] = __builtin_amdgcn_mfma_f32_16x16x32_bf16(a[i], b[j], acc[i][j], 0, 0, 0);
        PIPE_EXIT()
    }

    // 4-pass epilogue: stage 32 scaled-bf16 rows in Ps, convert+store coalesced uint4.
#pragma unroll
    for (int pp = 0; pp < 4; pp++) {
        if (wm == (pp >> 1)) {
#pragma unroll
            for (int ii = 0; ii < 2; ii++) {
                const int i = (pp & 1) * 2 + ii;       // compile-time acc index
                int lr = ii * 16 + quad * 4;           // local row in [0,32)
#pragma unroll
                for (int r = 0; r < 4; r++) {
#pragma unroll
                    for (int j = 0; j < 4; j++) {
                        int col = wn * 64 + j * 16 + l16;
                        Ps[(lr + r) * 136 + col] = bfbits(acc[i][j][r] * VSCALE);
                    }
                }
            }
        }
        __syncthreads();
        {
            int row = t >> 3;            // 0..31
            int col = (t & 7) * 16;      // 0..112 step 16
            int gm = row0 + pp * 32 + row;
            if (gm < N_) {
                uint4 ua = *(const uint4*)&Ps[row * 136 + col];
                uint4 ub = *(const uint4*)&Ps[row * 136 + col + 8];
                unsigned p0 = __builtin_amdgcn_cvt_pk_fp8_f32(bf_lo(ua.x), bf_hi(ua.x), 0, false);
                p0 = __builtin_amdgcn_cvt_pk_fp8_f32(bf_lo(ua.y), bf_hi(ua.y), p0, true);
                unsigned p1 = __builtin_amdgcn_cvt_pk_fp8_f32(bf_lo(ua.z), bf_hi(ua.z), 0, false);
                p1 = __builtin_amdgcn_cvt_pk_fp8_f32(bf_lo(ua.w), bf_hi(ua.w), p1, true);
                unsigned p2 = __builtin_amdgcn_cvt_pk_fp8_f32(bf_lo(ub.x), bf_hi(ub.x), 0, false);
                p2 = __builtin_amdgcn_cvt_pk_fp8_f32(bf_lo(ub.y), bf_hi(ub.y), p2, true);
                unsigned p3 = __builtin_amdgcn_cvt_pk_fp8_f32(bf_lo(ub.z), bf_hi(ub.z), 0, false);
                p3 = __builtin_amdgcn_cvt_pk_fp8_f32(bf_lo(ub.w), bf_hi(ub.w), p3, true);
                uint4 o4;
                o4.x = p0; o4.y = p1; o4.z = p2; o4.w = p3;
                *(uint4*)(V8 + (size_t)gm * NV_ + col0 + col) = o4;
            }
        }
        __syncthreads();
    }
}

// Tail GEMM with packed B (384x512): cols 0..255 -> relu->o1bf; cols 256..383 -> h1.
__global__ __launch_bounds__(256, 3) void k_gemm_tail(const __hip_bfloat16* __restrict__ A,
                                                      const __hip_bfloat16* __restrict__ Bpk,
                                                      const float* __restrict__ b1,
                                                      const float* __restrict__ b2,
                                                      __hip_bfloat16* __restrict__ o1bf,
                                                      float* __restrict__ h1) {
    __shared__ __align__(16) short As[2][4096];
    __shared__ __align__(16) short Bs[2][4096];
    int t = threadIdx.x;
    int lane = t & 63, wave = t >> 6;
    int wm = wave >> 1, wn = wave & 1;
    int quad = lane >> 4, l16 = lane & 15;
    int row0 = blockIdx.y * 128, col0 = blockIdx.x * 128;

    f32x4 acc[4][4] = {};
    int r_ld = (lane >> 2);
    int koff = (((lane & 3) ^ ((lane >> 3) & 3)) * 8);
    int swz = (l16 >> 1) & 3;

    auto stage = [&](int buf, int k0) {
#pragma unroll
        for (int c = 0; c < 4; c++) {
            int q = wave * 4 + c;
            int ch = q & 7;
            int r = ch * 16 + r_ld;
            const __hip_bfloat16* gp;
            short* lp;
            if (q < 8) { gp = A   + (size_t)(row0 + r) * 512 + k0 + koff; lp = &As[buf][ch * 512]; }
            else       { gp = Bpk + (size_t)(col0 + r) * 512 + k0 + koff; lp = &Bs[buf][ch * 512]; }
            __builtin_amdgcn_global_load_lds(
                (const __attribute__((address_space(1))) unsigned int*)(uintptr_t)gp,
                (__attribute__((address_space(3))) unsigned int*)(uintptr_t)lp,
                16, 0, 0);
        }
    };

    stage(0, 0);
    for (int kk = 0; kk < 16; kk++) {
        int cur = kk & 1;
        if (kk + 1 < 16) {
            stage(cur ^ 1, (kk + 1) * 32);
            PIPE_WAIT_ENTER(4)
        } else {
            PIPE_WAIT_ENTER(0)
        }
        bf16x8 a[4], b[4];
#pragma unroll
        for (int i = 0; i < 4; i++)
            a[i] = *(const bf16x8*)&As[cur][(wm * 64 + i * 16 + l16) * 32 + ((quad ^ swz) << 3)];
#pragma unroll
        for (int j = 0; j < 4; j++)
            b[j] = *(const bf16x8*)&Bs[cur][(wn * 64 + j * 16 + l16) * 32 + ((quad ^ swz) << 3)];
#pragma unroll
        for (int i = 0; i < 4; i++)
#pragma unroll
            for (int j = 0; j < 4; j++)
                acc[i][j] = __builtin_amdgcn_mfma_f32_16x16x32_bf16(a[i], b[j], acc[i][j], 0, 0, 0);
        PIPE_EXIT()
    }

#pragma unroll
    for (int i = 0; i < 4; i++) {
        int gm0 = row0 + wm * 64 + i * 16 + quad * 4;
#pragma unroll
        for (int r = 0; r < 4; r++) {
            int gm = gm0 + r;
#pragma unroll
            for (int j = 0; j < 4; j++) {
                int col = col0 + wn * 64 + l16 + j * 16;
                float v = acc[i][j][r];
                if (col < 256) {
                    v = fmaxf(v + b1[col], 0.f);
                    o1bf[(size_t)gm * H_ + col] = __float2bfloat16(v);
                } else {
                    h1[(size_t)gm * 128 + (col - 256)] = v + b2[col - 256];
                }
            }
        }
    }
}

// msg[e,o] = (he[e,:]/64).(fp8 V[row[e],o,:]) + outb[row[e],o]; atomicAdd into agg[col[e],o]
// V8 layout [n][k16][o][16]: thread o's chunk for k-group q is at q*4096 + o*16
// -> each wave reads 1 KB contiguous per instruction (fully coalesced).
__global__ void k_msg(const int* __restrict__ ei, const float* __restrict__ he,
                      const unsigned char* __restrict__ V8, const float* __restrict__ outb,
                      float* __restrict__ agg) {
    int e = blockIdx.x, o = threadIdx.x;
    __shared__ float hs[KH_];
    if (o < KH_) hs[o] = he[e * KH_ + o] * VSCALE_INV;
    __syncthreads();
    int r = ei[e], c = ei[E_ + e];
    float acc = outb[(size_t)r * H_ + o];
    const unsigned char* vbase = V8 + (size_t)r * NV_ + o * 16;
#pragma unroll
    for (int q = 0; q < 8; q++) {       // 8 x 16B chunks, stride 4096
        uint4 u = *(const uint4*)(vbase + (size_t)q * 4096);
        const float* hp = hs + q * 16;
        f32x2 f;
        f = __builtin_amdgcn_cvt_pk_f32_fp8(u.x, false); acc += hp[0]  * f.x + hp[1]  * f.y;
        f = __builtin_amdgcn_cvt_pk_f32_fp8(u.x, true);  acc += hp[2]  * f.x + hp[3]  * f.y;
        f = __builtin_amdgcn_cvt_pk_f32_fp8(u.y, false); acc += hp[4]  * f.x + hp[5]  * f.y;
        f = __builtin_amdgcn_cvt_pk_f32_fp8(u.y, true);  acc += hp[6]  * f.x + hp[7]  * f.y;
        f = __builtin_amdgcn_cvt_pk_f32_fp8(u.z, false); acc += hp[8]  * f.x + hp[9]  * f.y;
        f = __builtin_amdgcn_cvt_pk_f32_fp8(u.z, true);  acc += hp[10] * f.x + hp[11] * f.y;
        f = __builtin_amdgcn_cvt_pk_f32_fp8(u.w, false); acc += hp[12] * f.x + hp[13] * f.y;
        f = __builtin_amdgcn_cvt_pk_f32_fp8(u.w, true);  acc += hp[14] * f.x + hp[15] * f.y;
    }
    atomicAdd(&agg[(size_t)c * H_ + o], acc);
}

// Mbf = bf16(relu(agg / max(counts,1) + conv_b)); zeroes agg for the next iteration.
__global__ void k_m(float* __restrict__ agg, const float* __restrict__ counts,
                    const float* __restrict__ conv_b, __hip_bfloat16* __restrict__ Mbf) {
    int i = blockIdx.x * blockDim.x + threadIdx.x;
    if (i >= N_ * H_) return;
    int n = i >> 8, o = i & 255;
    float c = fmaxf(counts[n], 1.0f);
    float a = agg[i];
    agg[i] = 0.f;
    Mbf[i] = __float2bfloat16(fmaxf(a / c + conv_b[o], 0.f));
}

// GRU pointwise; also refreshes Abf = bf16(h)
__global__ void k_gru_update(const float* __restrict__ gi, const float* __restrict__ gh,
                             float* __restrict__ h, __hip_bfloat16* __restrict__ Abf) {
    int i = blockIdx.x * blockDim.x + threadIdx.x;
    if (i >= N_ * H_) return;
    int n = i >> 8, j = i & 255;
    const float* gip = gi + (size_t)n * NG_;
    const float* ghp = gh + (size_t)n * NG_;
    float r = 1.f / (1.f + expf(-(gip[j] + ghp[j])));
    float z = 1.f / (1.f + expf(-(gip[H_ + j] + ghp[H_ + j])));
    float nn = tanhf(gip[2 * H_ + j] + r * ghp[2 * H_ + j]);
    float hv = (1.f - z) * nn + z * h[i];
    h[i] = hv;
    Abf[i] = __float2bfloat16(hv);
}

// batchnorm stats over E rows, per column j   grid 128, block 256
__global__ void k_bnstats(const float* __restrict__ h1, float* __restrict__ mu,
                          float* __restrict__ rsig) {
    int j = blockIdx.x, t = threadIdx.x;
    float s = 0.f, ss = 0.f;
    for (int e = t; e < E_; e += 256) {
        float v = h1[(size_t)e * 128 + j];
        s += v;
        ss += v * v;
    }
    __shared__ float rs[256], rss[256];
    rs[t] = s; rss[t] = ss;
    __syncthreads();
    for (int off = 128; off > 0; off >>= 1) {
        if (t < off) { rs[t] += rs[t + off]; rss[t] += rss[t + off]; }
        __syncthreads();
    }
    if (t == 0) {
        float m_ = rs[0] / E_;
        float v_ = rss[0] / E_ - m_ * m_;
        mu[j] = m_;
        rsig[j] = rsqrtf(v_ + 1e-5f);
    }
}

// precs[e] = relu(bn(h1[e])) . l6_W2 + b
__global__ void k_precs(const float* __restrict__ h1, const float* __restrict__ mu,
                        const float* __restrict__ rsig, const float* __restrict__ g,
                        const float* __restrict__ bb, const float* __restrict__ W2,
                        const float* __restrict__ b2, float* __restrict__ out) {
    int e = blockIdx.x * blockDim.x + threadIdx.x;
    if (e >= E_) return;
    float acc = b2[0];
#pragma unroll 4
    for (int j = 0; j < 128; j++) {
        float v = (h1[(size_t)e * 128 + j] - mu[j]) * rsig[j] * g[j] + bb[j];
        acc += fmaxf(v, 0.f) * W2[j];
    }
    out[(size_t)E_ * 242 + e] = acc;
}

extern "C" void kernel_launch(void* const* d_in, const int* in_sizes, int n_in,
                              void* d_out, int out_size, void* d_ws, size_t ws_size,
                              hipStream_t stream) {
    const int*   x        = (const int*)  d_in[0];
    const float* pos      = (const float*)d_in[1];
    const int*   ei       = (const int*)  d_in[2];
    const float* edge_atr = (const float*)d_in[3];
    const float* emb      = (const float*)d_in[4];
    const float* lin0_W   = (const float*)d_in[5];
    const float* lin0_b   = (const float*)d_in[6];
    const float* mlp1_W   = (const float*)d_in[7];
    const float* mlp1_b   = (const float*)d_in[8];
    const float* mlp2_W   = (const float*)d_in[9];
    const float* mlp2_b   = (const float*)d_in[10];
    const float* conv_b   = (const float*)d_in[11];
    const float* gru_Wih  = (const float*)d_in[12];
    const float* gru_Whh  = (const float*)d_in[13];
    const float* gru_bih  = (const float*)d_in[14];
    const float* gru_bhh  = (const float*)d_in[15];
    const float* lin1_W   = (const float*)d_in[16];
    const float* lin1_b   = (const float*)d_in[17];
    const float* lin2_W   = (const float*)d_in[18];
    const float* lin2_b   = (const float*)d_in[19];
    const float* l6_W1    = (const float*)d_in[20];
    const float* l6_b1    = (const float*)d_in[21];
    const float* bn_g     = (const float*)d_in[22];
    const float* bn_b     = (const float*)d_in[23];
    const float* l6_W2    = (const float*)d_in[24];
    const float* l6_b2    = (const float*)d_in[25];
    float* out = (float*)d_out;

    // workspace layout
    char* w = (char*)d_ws;
    size_t off = 0;
    auto alloc = [&](size_t bytes) -> void* {
        void* p = w + off;
        off = (off + bytes + 255) & ~(size_t)255;
        return p;
    };
    float* hbuf   = (float*)alloc((size_t)N_ * H_ * 4);
    float* aggm   = (float*)alloc((size_t)N_ * H_ * 4);
    float* outb   = (float*)alloc((size_t)N_ * H_ * 4);
    float* he     = (float*)alloc((size_t)E_ * KH_ * 4);
    float* gi     = (float*)alloc((size_t)N_ * NG_ * 4);
    float* gh     = (float*)alloc((size_t)N_ * NG_ * 4);
    float* h1     = (float*)alloc((size_t)E_ * 128 * 4);
    float* counts = (float*)alloc((size_t)N_ * 4);
    float* mu     = (float*)alloc(128 * 4);
    float* rsig   = (float*)alloc(128 * 4);
    unsigned char* V8      = (unsigned char*)alloc((size_t)N_ * NV_);          // 65.5 MB fp8
    __hip_bfloat16* Abf    = (__hip_bfloat16*)alloc((size_t)MPAD_ * H_ * 2);
    __hip_bfloat16* Mbf    = (__hip_bfloat16*)alloc((size_t)MPAD_ * H_ * 2);
    __hip_bfloat16* Bt     = (__hip_bfloat16*)alloc((size_t)NV_ * H_ * 2);     // 16.8 MB
    __hip_bfloat16* WihB   = (__hip_bfloat16*)alloc((size_t)NG_ * H_ * 2);
    __hip_bfloat16* WhhB   = (__hip_bfloat16*)alloc((size_t)NG_ * H_ * 2);
    __hip_bfloat16* Bpk    = (__hip_bfloat16*)alloc((size_t)384 * 512 * 2);
    __hip_bfloat16* lin2Wb = (__hip_bfloat16*)alloc((size_t)H_ * H_ * 2);
    __hip_bfloat16* BtB    = (__hip_bfloat16*)alloc((size_t)H_ * H_ * 2);
    __hip_bfloat16* Cbf    = (__hip_bfloat16*)alloc((size_t)E_ * 2 * H_ * 2);
    __hip_bfloat16* o1bf   = (__hip_bfloat16*)alloc((size_t)E_ * H_ * 2);

    k_lin0<<<MPAD_, 256, 0, stream>>>(x, pos, emb, lin0_W, lin0_b, hbuf, Abf);
    k_he<<<E_, 128, 0, stream>>>(edge_atr, mlp1_W, mlp1_b, he);
    hipMemsetAsync(counts, 0, (size_t)N_ * 4, stream);
    hipMemsetAsync(aggm, 0, (size_t)N_ * H_ * 4, stream);
    k_counts<<<(E_ + 255) / 256, 256, 0, stream>>>(ei, counts);
    k_trans_bt<<<dim3(NV_ / 64, H_ / 32), 256, 0, stream>>>(mlp2_W, Bt);
    k_prep_w<<<768, 256, 0, stream>>>(gru_Wih, gru_Whh, lin1_W, l6_W1, lin2_W, mlp2_b,
                                      WihB, WhhB, Bpk, lin2Wb, BtB);

    for (int it = 0; it < 3; it++) {
        // fused: gh = Abf@Whh^T + bhh, outb = Abf@BtB^T, V8 = fp8(Abf@Bt^T)
        k_gemm_VP<<<128 + (NV_ / 128) * (MPAD_ / 128), 256, 0, stream>>>(
            Abf, Bt, WhhB, BtB, gru_bhh, gh, outb, V8);
        k_msg<<<E_, 256, 0, stream>>>(ei, he, V8, outb, aggm);
        k_m<<<(N_ * H_ + 255) / 256, 256, 0, stream>>>(aggm, counts, conv_b, Mbf);
        // gi = Mbf @ Wih^T + bih
        k_gemm_nt<256, false, false><<<dim3(6, MPAD_ / 128), 256, 0, stream>>>(
            Mbf, WihB, gi, nullptr, gru_bih, NG_, NG_, N_);
        k_gru_update<<<(N_ * H_ + 255) / 256, 256, 0, stream>>>(gi, gh, hbuf, Abf);
    }

    k_concat<<<E_, 256, 0, stream>>>(ei, hbuf, Cbf);
    k_gemm_tail<<<dim3(3, E_ / 128), 256, 0, stream>>>(Cbf, Bpk, lin1_b, l6_b1, o1bf, h1);
    k_gemm_nt<256, false, false><<<dim3(2, E_ / 128), 256, 0, stream>>>(
        o1bf, lin2Wb, out, nullptr, lin2_b, 242, 242, E_);
    k_bnstats<<<128, 256, 0, stream>>>(h1, mu, rsig);
    k_precs<<<(E_ + 255) / 256, 256, 0, stream>>>(h1, mu, rsig, bn_g, bn_b, l6_W2, l6_b2, out);
}

// Round 5
// 458.943 us; speedup vs baseline: 1.4095x; 1.0134x over previous
//
#include <hip/hip_runtime.h>
#include <hip/hip_bf16.h>

// Problem constants (fixed by the reference)
constexpr int N_ = 2000;   // nodes
constexpr int E_ = 4096;   // edges
constexpr int H_ = 256;    // hidden
constexpr int KH_ = 128;   // he dim (mlp1 out)
constexpr int NV_ = H_ * KH_; // 32768, V row length — fp8 bytes
constexpr int MPAD_ = 2048;   // padded M for node-side MFMA GEMMs
constexpr int NG_ = 768;      // GRU gate width (3*H)
constexpr float VSCALE = 64.f;     // fp8 scale for V (avoids e4m3 subnormals)
constexpr float VSCALE_INV = 1.f / 64.f;

typedef short bf16x8 __attribute__((ext_vector_type(8)));
typedef float f32x4  __attribute__((ext_vector_type(4)));
typedef float f32x2  __attribute__((ext_vector_type(2)));

__device__ __forceinline__ float bf_lo(unsigned u) { return __uint_as_float(u << 16); }
__device__ __forceinline__ float bf_hi(unsigned u) { return __uint_as_float(u & 0xffff0000u); }
__device__ __forceinline__ short bfbits(float f) {
    __hip_bfloat16 b = __float2bfloat16(f);
    return *(short*)&b;
}

// ---- pipeline sync helpers (T4: counted vmcnt across raw barrier), depth-2 ----
#define PIPE_WAIT_ENTER(N_OUTST)                                   \
    asm volatile("s_waitcnt vmcnt(" #N_OUTST ")" ::: "memory");    \
    __builtin_amdgcn_s_barrier();                                  \
    asm volatile("" ::: "memory");                                 \
    __builtin_amdgcn_sched_barrier(0);

#define PIPE_EXIT()                                                \
    __builtin_amdgcn_sched_barrier(0);                             \
    asm volatile("" ::: "memory");                                 \
    __builtin_amdgcn_s_barrier();

// out = relu([emb[x], pos] @ lin0_W.T + b); also emits Abf (bf16, zero-padded rows).
__global__ void k_lin0(const int* __restrict__ x, const float* __restrict__ pos,
                       const float* __restrict__ emb, const float* __restrict__ W,
                       const float* __restrict__ b, float* __restrict__ out,
                       __hip_bfloat16* __restrict__ Abf) {
    int n = blockIdx.x, t = threadIdx.x;
    if (n >= N_) { Abf[(size_t)n * H_ + t] = __float2bfloat16(0.f); return; }
    __shared__ float in_p[8];
    if (t < 5) in_p[t] = emb[x[n] * 5 + t];
    else if (t < 8) in_p[t] = pos[n * 3 + (t - 5)];
    __syncthreads();
    float acc = b[t];
#pragma unroll
    for (int i = 0; i < 8; i++) acc += in_p[i] * W[t * 8 + i];
    float v = fmaxf(acc, 0.f);
    out[n * H_ + t] = v;
    Abf[(size_t)n * H_ + t] = __float2bfloat16(v);
}

// he = relu(edge_atr @ mlp1_W.T + b)   grid E, block 128
__global__ void k_he(const float* __restrict__ ea, const float* __restrict__ W,
                     const float* __restrict__ b, float* __restrict__ he) {
    int e = blockIdx.x, t = threadIdx.x;
    __shared__ float a[5];
    if (t < 5) a[t] = ea[e * 5 + t];
    __syncthreads();
    float acc = b[t];
#pragma unroll
    for (int i = 0; i < 5; i++) acc += a[i] * W[t * 5 + i];
    he[e * KH_ + t] = fmaxf(acc, 0.f);
}

__global__ void k_counts(const int* __restrict__ ei, float* __restrict__ counts) {
    int e = blockIdx.x * blockDim.x + threadIdx.x;
    if (e < E_) atomicAdd(&counts[ei[E_ + e]], 1.0f);
}

// Bt[nv][h] = mlp2_W[h*32768 + nv] as bf16 (transpose+convert), once per launch.
// float4 loads, short4 stores.
__global__ void k_trans_bt(const float* __restrict__ W, __hip_bfloat16* __restrict__ Bt) {
    __shared__ float tile[32][68];   // 68: 16B-aligned rows, bank-shifted
    int t = threadIdx.x;
    int n0 = blockIdx.x * 64, k0 = blockIdx.y * 32;
#pragma unroll
    for (int i = 0; i < 2; i++) {
        int idx = t + i * 256;                 // 0..511
        int kk = idx >> 4, nn = (idx & 15) * 4;
        float4 f = *(const float4*)&W[(size_t)(k0 + kk) * NV_ + n0 + nn];
        *(float4*)&tile[kk][nn] = f;
    }
    __syncthreads();
#pragma unroll
    for (int i = 0; i < 2; i++) {
        int idx = t + i * 256;                 // 0..511
        int nn = idx >> 3, k4 = (idx & 7) * 4;
        short4 s;
        s.x = bfbits(tile[k4 + 0][nn]);
        s.y = bfbits(tile[k4 + 1][nn]);
        s.z = bfbits(tile[k4 + 2][nn]);
        s.w = bfbits(tile[k4 + 3][nn]);
        *(short4*)&Bt[(size_t)(n0 + nn) * H_ + k0 + k4] = s;
    }
}

// One-time weight preps (bf16 converts + packed tail B + lin2 pad + mlp2_b transpose).
__global__ void k_prep_w(const float* __restrict__ Wih, const float* __restrict__ Whh,
                         const float* __restrict__ lin1W, const float* __restrict__ l6W1,
                         const float* __restrict__ lin2W, const float* __restrict__ b2,
                         __hip_bfloat16* __restrict__ WihB, __hip_bfloat16* __restrict__ WhhB,
                         __hip_bfloat16* __restrict__ Bpk,
                         __hip_bfloat16* __restrict__ lin2Wb, __hip_bfloat16* __restrict__ BtB) {
    int i = blockIdx.x * 256 + threadIdx.x;     // i < 196608
    if (i < NG_ * H_) {
        WihB[i] = __float2bfloat16(Wih[i]);
        WhhB[i] = __float2bfloat16(Whh[i]);
    }
    Bpk[i] = __float2bfloat16(i < 256 * 512 ? lin1W[i] : l6W1[i - 256 * 512]);
    if (i < 128 * 2 * H_) {
        int r = i >> 8, k = i & 255;
        lin2Wb[i] = __float2bfloat16(r < 242 ? lin2W[r * H_ + k] : 0.f);
        int o = i >> 8, h = i & 255;
        BtB[o * H_ + h] = __float2bfloat16(b2[h * H_ + o]);
    }
}

// Cbf[e] = bf16([h[row[e]], h[col[e]]])   grid E, block 256
__global__ void k_concat(const int* __restrict__ ei, const float* __restrict__ h,
                         __hip_bfloat16* __restrict__ Cbf) {
    int e = blockIdx.x, t = threadIdx.x;
    int r = ei[e], c = ei[E_ + e];
    Cbf[(size_t)e * 512 + t]       = __float2bfloat16(h[(size_t)r * H_ + t]);
    Cbf[(size_t)e * 512 + 256 + t] = __float2bfloat16(h[(size_t)c * H_ + t]);
}

// Generic MFMA GEMM: C(MxN) = A(MxKD bf16) @ Bt(NxKD bf16)^T [+bias][relu].
// Depth-2 pipeline (counted vmcnt(4) across raw barrier).
template <int KD, bool RELU, bool OUT_BF16>
__global__ __launch_bounds__(256, 3) void k_gemm_nt(const __hip_bfloat16* __restrict__ A,
                                                    const __hip_bfloat16* __restrict__ Bt,
                                                    float* __restrict__ Cf,
                                                    __hip_bfloat16* __restrict__ Cb,
                                                    const float* __restrict__ bias,
                                                    int ldc, int ncols, int mvalid) {
    __shared__ __align__(16) short As[2][4096];
    __shared__ __align__(16) short Bs[2][4096];
    int t = threadIdx.x;
    int lane = t & 63, wave = t >> 6;
    int wm = wave >> 1, wn = wave & 1;
    int quad = lane >> 4, l16 = lane & 15;
    int row0 = blockIdx.y * 128, col0 = blockIdx.x * 128;

    f32x4 acc[4][4] = {};
    int r_ld = (lane >> 2);
    int koff = (((lane & 3) ^ ((lane >> 3) & 3)) * 8);  // swizzled 16B slot
    int swz = (l16 >> 1) & 3;                           // read-side slot XOR
    constexpr int NST = KD / 32;

    auto stage = [&](int buf, int k0) {
#pragma unroll
        for (int c = 0; c < 4; c++) {
            int q = wave * 4 + c;
            int ch = q & 7;
            int r = ch * 16 + r_ld;
            const __hip_bfloat16* gp;
            short* lp;
            if (q < 8) { gp = A  + (size_t)(row0 + r) * KD + k0 + koff; lp = &As[buf][ch * 512]; }
            else       { gp = Bt + (size_t)(col0 + r) * KD + k0 + koff; lp = &Bs[buf][ch * 512]; }
            __builtin_amdgcn_global_load_lds(
                (const __attribute__((address_space(1))) unsigned int*)(uintptr_t)gp,
                (__attribute__((address_space(3))) unsigned int*)(uintptr_t)lp,
                16, 0, 0);
        }
    };

    stage(0, 0);
    for (int kk = 0; kk < NST; kk++) {
        int cur = kk & 1;
        if (kk + 1 < NST) {
            stage(cur ^ 1, (kk + 1) * 32);
            PIPE_WAIT_ENTER(4)
        } else {
            PIPE_WAIT_ENTER(0)
        }
        bf16x8 a[4], b[4];
#pragma unroll
        for (int i = 0; i < 4; i++)
            a[i] = *(const bf16x8*)&As[cur][(wm * 64 + i * 16 + l16) * 32 + ((quad ^ swz) << 3)];
#pragma unroll
        for (int j = 0; j < 4; j++)
            b[j] = *(const bf16x8*)&Bs[cur][(wn * 64 + j * 16 + l16) * 32 + ((quad ^ swz) << 3)];
#pragma unroll
        for (int i = 0; i < 4; i++)
#pragma unroll
            for (int j = 0; j < 4; j++)
                acc[i][j] = __builtin_amdgcn_mfma_f32_16x16x32_bf16(a[i], b[j], acc[i][j], 0, 0, 0);
        PIPE_EXIT()
    }

#pragma unroll
    for (int i = 0; i < 4; i++) {
        int gm0 = row0 + wm * 64 + i * 16 + quad * 4;
#pragma unroll
        for (int r = 0; r < 4; r++) {
            int gm = gm0 + r;
            if (gm < mvalid) {
#pragma unroll
                for (int j = 0; j < 4; j++) {
                    int col = col0 + wn * 64 + l16 + j * 16;
                    if (col < ncols) {
                        float v = acc[i][j][r];
                        if (bias) v += bias[col];
                        if (RELU) v = fmaxf(v, 0.f);
                        if (OUT_BF16) Cb[(size_t)gm * ldc + col] = __float2bfloat16(v);
                        else          Cf[(size_t)gm * ldc + col] = v;
                    }
                }
            }
        }
    }
}

// Fused per-iteration GEMM launch (one grid, block-uniform branch):
//   blocks [0,128):    pair part — pbx=bid&7, pby=bid>>3
//       pbx 0..5: gh = Abf @ WhhB^T + bhh  (ldc 768)
//       pbx 6..7: outb = Abf @ BtB^T       (ldc 256)
//   blocks [128,4224): V part — vb=bid-128, bx=vb&255, by=vb>>8
//       V = Abf @ Bt^T -> fp8 e4m3 (x64), permuted layout V8[n][k16][o][16]
// __launch_bounds__(256,4): cap regs at 128/wave (64 arch + 64 AGPR acc) so
// 4 blocks/CU co-reside (LDS 32KB allows 5) — cross-block TLP covers the
// counted-vmcnt wait (m114: separate blocks' MFMA overlap freely).
__global__ __launch_bounds__(256, 4) void k_gemm_VP(const __hip_bfloat16* __restrict__ Abf,
                                                    const __hip_bfloat16* __restrict__ Bt,
                                                    const __hip_bfloat16* __restrict__ WhhB,
                                                    const __hip_bfloat16* __restrict__ BtB,
                                                    const float* __restrict__ bhh,
                                                    float* __restrict__ gh,
                                                    float* __restrict__ outb,
                                                    unsigned char* __restrict__ V8) {
    __shared__ __align__(16) short As[2][4096];
    __shared__ __align__(16) short Bs[2][4096];
    int bid = blockIdx.x;
    int t = threadIdx.x;
    int lane = t & 63, wave = t >> 6;
    int wm = wave >> 1, wn = wave & 1;
    int quad = lane >> 4, l16 = lane & 15;
    int r_ld = (lane >> 2);
    int koff = (((lane & 3) ^ ((lane >> 3) & 3)) * 8);
    int swz = (l16 >> 1) & 3;

    if (bid < 128) {
        // ---------------- pair part ----------------
        int pbx = bid & 7, pby = bid >> 3;
        bool ob = (pbx >= 6);
        const __hip_bfloat16* Bp = ob ? BtB : WhhB;
        int col0 = ob ? (pbx - 6) * 128 : pbx * 128;
        int ldc = ob ? H_ : NG_;
        float* C = ob ? outb : gh;
        int row0 = pby * 128;

        f32x4 acc[4][4] = {};
        auto stage = [&](int buf, int k0) {
#pragma unroll
            for (int c = 0; c < 4; c++) {
                int q = wave * 4 + c;
                int ch = q & 7;
                int r = ch * 16 + r_ld;
                const __hip_bfloat16* gp;
                short* lp;
                if (q < 8) { gp = Abf + ((size_t)(row0 + r) << 8) + k0 + koff; lp = &As[buf][ch * 512]; }
                else       { gp = Bp  + ((size_t)(col0 + r) << 8) + k0 + koff; lp = &Bs[buf][ch * 512]; }
                __builtin_amdgcn_global_load_lds(
                    (const __attribute__((address_space(1))) unsigned int*)(uintptr_t)gp,
                    (__attribute__((address_space(3))) unsigned int*)(uintptr_t)lp,
                    16, 0, 0);
            }
        };
        stage(0, 0);
        for (int kk = 0; kk < 8; kk++) {
            int cur = kk & 1;
            if (kk + 1 < 8) {
                stage(cur ^ 1, (kk + 1) * 32);
                PIPE_WAIT_ENTER(4)
            } else {
                PIPE_WAIT_ENTER(0)
            }
            bf16x8 a[4], b[4];
#pragma unroll
            for (int i = 0; i < 4; i++)
                a[i] = *(const bf16x8*)&As[cur][(wm * 64 + i * 16 + l16) * 32 + ((quad ^ swz) << 3)];
#pragma unroll
            for (int j = 0; j < 4; j++)
                b[j] = *(const bf16x8*)&Bs[cur][(wn * 64 + j * 16 + l16) * 32 + ((quad ^ swz) << 3)];
#pragma unroll
            for (int i = 0; i < 4; i++)
#pragma unroll
                for (int j = 0; j < 4; j++)
                    acc[i][j] = __builtin_amdgcn_mfma_f32_16x16x32_bf16(a[i], b[j], acc[i][j], 0, 0, 0);
            PIPE_EXIT()
        }
#pragma unroll
        for (int i = 0; i < 4; i++) {
            int gm0 = row0 + wm * 64 + i * 16 + quad * 4;
#pragma unroll
            for (int r = 0; r < 4; r++) {
                int gm = gm0 + r;
                if (gm < N_) {
#pragma unroll
                    for (int j = 0; j < 4; j++) {
                        int col = col0 + wn * 64 + l16 + j * 16;
                        float v = acc[i][j][r] + (ob ? 0.f : bhh[col]);
                        C[(size_t)gm * ldc + col] = v;
                    }
                }
            }
        }
        return;
    }

    // ---------------- V part ----------------
    int vb = bid - 128;
    int bx = vb & 255, by = vb >> 8;
    int row0 = by * 128, col0 = bx * 128;
    int obase = bx * 8;                    // o = (obase+ch)&255
    int kb = (bx >> 5) * 16;               // k16*16
    short* Ps = &As[0][0];                 // epilogue alias: 32 x 136 shorts

    f32x4 acc[4][4] = {};
    auto stage = [&](int buf, int k0) {
#pragma unroll
        for (int c = 0; c < 4; c++) {
            int q = wave * 4 + c;
            int ch = q & 7;
            const __hip_bfloat16* gp;
            short* lp;
            if (q < 8) {
                gp = Abf + ((size_t)(row0 + ch * 16 + r_ld) << 8) + k0 + koff;
                lp = &As[buf][ch * 512];
            } else {
                int nv = ((obase + ch) & 255) * 128 + kb + r_ld;   // f -> nv remap
                gp = Bt + ((size_t)nv << 8) + k0 + koff;
                lp = &Bs[buf][ch * 512];
            }
            __builtin_amdgcn_global_load_lds(
                (const __attribute__((address_space(1))) unsigned int*)(uintptr_t)gp,
                (__attribute__((address_space(3))) unsigned int*)(uintptr_t)lp,
                16, 0, 0);
        }
    };
    stage(0, 0);
    for (int kk = 0; kk < 8; kk++) {
        int cur = kk & 1;
        if (kk + 1 < 8) {
            stage(cur ^ 1, (kk + 1) * 32);
            PIPE_WAIT_ENTER(4)
        } else {
            PIPE_WAIT_ENTER(0)
        }
        bf16x8 a[4], b[4];
#pragma unroll
        for (int i = 0; i < 4; i++)
            a[i] = *(const bf16x8*)&As[cur][(wm * 64 + i * 16 + l16) * 32 + ((quad ^ swz) << 3)];
#pragma unroll
        for (int j = 0; j < 4; j++)
            b[j] = *(const bf16x8*)&Bs[cur][(wn * 64 + j * 16 + l16) * 32 + ((quad ^ swz) << 3)];
#pragma unroll
        for (int i = 0; i < 4; i++)
#pragma unroll
            for (int j = 0; j < 4; j++)
                acc[i][j] = __builtin_amdgcn_mfma_f32_16x16x32_bf16(a[i], b[j], acc[i][j], 0, 0, 0);
        PIPE_EXIT()
    }

    // 4-pass epilogue: stage 32 scaled-bf16 rows in Ps, convert+store coalesced uint4.
#pragma unroll
    for (int pp = 0; pp < 4; pp++) {
        if (wm == (pp >> 1)) {
#pragma unroll
            for (int ii = 0; ii < 2; ii++) {
                const int i = (pp & 1) * 2 + ii;       // compile-time acc index
                int lr = ii * 16 + quad * 4;           // local row in [0,32)
#pragma unroll
                for (int r = 0; r < 4; r++) {
#pragma unroll
                    for (int j = 0; j < 4; j++) {
                        int col = wn * 64 + j * 16 + l16;
                        Ps[(lr + r) * 136 + col] = bfbits(acc[i][j][r] * VSCALE);
                    }
                }
            }
        }
        __syncthreads();
        {
            int row = t >> 3;            // 0..31
            int col = (t & 7) * 16;      // 0..112 step 16
            int gm = row0 + pp * 32 + row;
            if (gm < N_) {
                uint4 ua = *(const uint4*)&Ps[row * 136 + col];
                uint4 ub = *(const uint4*)&Ps[row * 136 + col + 8];
                unsigned p0 = __builtin_amdgcn_cvt_pk_fp8_f32(bf_lo(ua.x), bf_hi(ua.x), 0, false);
                p0 = __builtin_amdgcn_cvt_pk_fp8_f32(bf_lo(ua.y), bf_hi(ua.y), p0, true);
                unsigned p1 = __builtin_amdgcn_cvt_pk_fp8_f32(bf_lo(ua.z), bf_hi(ua.z), 0, false);
                p1 = __builtin_amdgcn_cvt_pk_fp8_f32(bf_lo(ua.w), bf_hi(ua.w), p1, true);
                unsigned p2 = __builtin_amdgcn_cvt_pk_fp8_f32(bf_lo(ub.x), bf_hi(ub.x), 0, false);
                p2 = __builtin_amdgcn_cvt_pk_fp8_f32(bf_lo(ub.y), bf_hi(ub.y), p2, true);
                unsigned p3 = __builtin_amdgcn_cvt_pk_fp8_f32(bf_lo(ub.z), bf_hi(ub.z), 0, false);
                p3 = __builtin_amdgcn_cvt_pk_fp8_f32(bf_lo(ub.w), bf_hi(ub.w), p3, true);
                uint4 o4;
                o4.x = p0; o4.y = p1; o4.z = p2; o4.w = p3;
                *(uint4*)(V8 + (size_t)gm * NV_ + col0 + col) = o4;
            }
        }
        __syncthreads();
    }
}

// Tail GEMM with packed B (384x512): cols 0..255 -> relu->o1bf; cols 256..383 -> h1.
__global__ __launch_bounds__(256, 3) void k_gemm_tail(const __hip_bfloat16* __restrict__ A,
                                                      const __hip_bfloat16* __restrict__ Bpk,
                                                      const float* __restrict__ b1,
                                                      const float* __restrict__ b2,
                                                      __hip_bfloat16* __restrict__ o1bf,
                                                      float* __restrict__ h1) {
    __shared__ __align__(16) short As[2][4096];
    __shared__ __align__(16) short Bs[2][4096];
    int t = threadIdx.x;
    int lane = t & 63, wave = t >> 6;
    int wm = wave >> 1, wn = wave & 1;
    int quad = lane >> 4, l16 = lane & 15;
    int row0 = blockIdx.y * 128, col0 = blockIdx.x * 128;

    f32x4 acc[4][4] = {};
    int r_ld = (lane >> 2);
    int koff = (((lane & 3) ^ ((lane >> 3) & 3)) * 8);
    int swz = (l16 >> 1) & 3;

    auto stage = [&](int buf, int k0) {
#pragma unroll
        for (int c = 0; c < 4; c++) {
            int q = wave * 4 + c;
            int ch = q & 7;
            int r = ch * 16 + r_ld;
            const __hip_bfloat16* gp;
            short* lp;
            if (q < 8) { gp = A   + (size_t)(row0 + r) * 512 + k0 + koff; lp = &As[buf][ch * 512]; }
            else       { gp = Bpk + (size_t)(col0 + r) * 512 + k0 + koff; lp = &Bs[buf][ch * 512]; }
            __builtin_amdgcn_global_load_lds(
                (const __attribute__((address_space(1))) unsigned int*)(uintptr_t)gp,
                (__attribute__((address_space(3))) unsigned int*)(uintptr_t)lp,
                16, 0, 0);
        }
    };

    stage(0, 0);
    for (int kk = 0; kk < 16; kk++) {
        int cur = kk & 1;
        if (kk + 1 < 16) {
            stage(cur ^ 1, (kk + 1) * 32);
            PIPE_WAIT_ENTER(4)
        } else {
            PIPE_WAIT_ENTER(0)
        }
        bf16x8 a[4], b[4];
#pragma unroll
        for (int i = 0; i < 4; i++)
            a[i] = *(const bf16x8*)&As[cur][(wm * 64 + i * 16 + l16) * 32 + ((quad ^ swz) << 3)];
#pragma unroll
        for (int j = 0; j < 4; j++)
            b[j] = *(const bf16x8*)&Bs[cur][(wn * 64 + j * 16 + l16) * 32 + ((quad ^ swz) << 3)];
#pragma unroll
        for (int i = 0; i < 4; i++)
#pragma unroll
            for (int j = 0; j < 4; j++)
                acc[i][j] = __builtin_amdgcn_mfma_f32_16x16x32_bf16(a[i], b[j], acc[i][j], 0, 0, 0);
        PIPE_EXIT()
    }

#pragma unroll
    for (int i = 0; i < 4; i++) {
        int gm0 = row0 + wm * 64 + i * 16 + quad * 4;
#pragma unroll
        for (int r = 0; r < 4; r++) {
            int gm = gm0 + r;
#pragma unroll
            for (int j = 0; j < 4; j++) {
                int col = col0 + wn * 64 + l16 + j * 16;
                float v = acc[i][j][r];
                if (col < 256) {
                    v = fmaxf(v + b1[col], 0.f);
                    o1bf[(size_t)gm * H_ + col] = __float2bfloat16(v);
                } else {
                    h1[(size_t)gm * 128 + (col - 256)] = v + b2[col - 256];
                }
            }
        }
    }
}

// msg[e,o] = (he[e,:]/64).(fp8 V[row[e],o,:]) + outb[row[e],o]; atomicAdd into agg[col[e],o]
// V8 layout [n][k16][o][16]: thread o's chunk for k-group q is at q*4096 + o*16
// -> each wave reads 1 KB contiguous per instruction (fully coalesced).
__global__ void k_msg(const int* __restrict__ ei, const float* __restrict__ he,
                      const unsigned char* __restrict__ V8, const float* __restrict__ outb,
                      float* __restrict__ agg) {
    int e = blockIdx.x, o = threadIdx.x;
    __shared__ float hs[KH_];
    if (o < KH_) hs[o] = he[e * KH_ + o] * VSCALE_INV;
    __syncthreads();
    int r = ei[e], c = ei[E_ + e];
    float acc = outb[(size_t)r * H_ + o];
    const unsigned char* vbase = V8 + (size_t)r * NV_ + o * 16;
#pragma unroll
    for (int q = 0; q < 8; q++) {       // 8 x 16B chunks, stride 4096
        uint4 u = *(const uint4*)(vbase + (size_t)q * 4096);
        const float* hp = hs + q * 16;
        f32x2 f;
        f = __builtin_amdgcn_cvt_pk_f32_fp8(u.x, false); acc += hp[0]  * f.x + hp[1]  * f.y;
        f = __builtin_amdgcn_cvt_pk_f32_fp8(u.x, true);  acc += hp[2]  * f.x + hp[3]  * f.y;
        f = __builtin_amdgcn_cvt_pk_f32_fp8(u.y, false); acc += hp[4]  * f.x + hp[5]  * f.y;
        f = __builtin_amdgcn_cvt_pk_f32_fp8(u.y, true);  acc += hp[6]  * f.x + hp[7]  * f.y;
        f = __builtin_amdgcn_cvt_pk_f32_fp8(u.z, false); acc += hp[8]  * f.x + hp[9]  * f.y;
        f = __builtin_amdgcn_cvt_pk_f32_fp8(u.z, true);  acc += hp[10] * f.x + hp[11] * f.y;
        f = __builtin_amdgcn_cvt_pk_f32_fp8(u.w, false); acc += hp[12] * f.x + hp[13] * f.y;
        f = __builtin_amdgcn_cvt_pk_f32_fp8(u.w, true);  acc += hp[14] * f.x + hp[15] * f.y;
    }
    atomicAdd(&agg[(size_t)c * H_ + o], acc);
}

// Mbf = bf16(relu(agg / max(counts,1) + conv_b)); zeroes agg for the next iteration.
__global__ void k_m(float* __restrict__ agg, const float* __restrict__ counts,
                    const float* __restrict__ conv_b, __hip_bfloat16* __restrict__ Mbf) {
    int i = blockIdx.x * blockDim.x + threadIdx.x;
    if (i >= N_ * H_) return;
    int n = i >> 8, o = i & 255;
    float c = fmaxf(counts[n], 1.0f);
    float a = agg[i];
    agg[i] = 0.f;
    Mbf[i] = __float2bfloat16(fmaxf(a / c + conv_b[o], 0.f));
}

// GRU pointwise; also refreshes Abf = bf16(h)
__global__ void k_gru_update(const float* __restrict__ gi, const float* __restrict__ gh,
                             float* __restrict__ h, __hip_bfloat16* __restrict__ Abf) {
    int i = blockIdx.x * blockDim.x + threadIdx.x;
    if (i >= N_ * H_) return;
    int n = i >> 8, j = i & 255;
    const float* gip = gi + (size_t)n * NG_;
    const float* ghp = gh + (size_t)n * NG_;
    float r = 1.f / (1.f + expf(-(gip[j] + ghp[j])));
    float z = 1.f / (1.f + expf(-(gip[H_ + j] + ghp[H_ + j])));
    float nn = tanhf(gip[2 * H_ + j] + r * ghp[2 * H_ + j]);
    float hv = (1.f - z) * nn + z * h[i];
    h[i] = hv;
    Abf[i] = __float2bfloat16(hv);
}

// batchnorm stats over E rows, per column j   grid 128, block 256
__global__ void k_bnstats(const float* __restrict__ h1, float* __restrict__ mu,
                          float* __restrict__ rsig) {
    int j = blockIdx.x, t = threadIdx.x;
    float s = 0.f, ss = 0.f;
    for (int e = t; e < E_; e += 256) {
        float v = h1[(size_t)e * 128 + j];
        s += v;
        ss += v * v;
    }
    __shared__ float rs[256], rss[256];
    rs[t] = s; rss[t] = ss;
    __syncthreads();
    for (int off = 128; off > 0; off >>= 1) {
        if (t < off) { rs[t] += rs[t + off]; rss[t] += rss[t + off]; }
        __syncthreads();
    }
    if (t == 0) {
        float m_ = rs[0] / E_;
        float v_ = rss[0] / E_ - m_ * m_;
        mu[j] = m_;
        rsig[j] = rsqrtf(v_ + 1e-5f);
    }
}

// precs[e] = relu(bn(h1[e])) . l6_W2 + b
__global__ void k_precs(const float* __restrict__ h1, const float* __restrict__ mu,
                        const float* __restrict__ rsig, const float* __restrict__ g,
                        const float* __restrict__ bb, const float* __restrict__ W2,
                        const float* __restrict__ b2, float* __restrict__ out) {
    int e = blockIdx.x * blockDim.x + threadIdx.x;
    if (e >= E_) return;
    float acc = b2[0];
#pragma unroll 4
    for (int j = 0; j < 128; j++) {
        float v = (h1[(size_t)e * 128 + j] - mu[j]) * rsig[j] * g[j] + bb[j];
        acc += fmaxf(v, 0.f) * W2[j];
    }
    out[(size_t)E_ * 242 + e] = acc;
}

extern "C" void kernel_launch(void* const* d_in, const int* in_sizes, int n_in,
                              void* d_out, int out_size, void* d_ws, size_t ws_size,
                              hipStream_t stream) {
    const int*   x        = (const int*)  d_in[0];
    const float* pos      = (const float*)d_in[1];
    const int*   ei       = (const int*)  d_in[2];
    const float* edge_atr = (const float*)d_in[3];
    const float* emb      = (const float*)d_in[4];
    const float* lin0_W   = (const float*)d_in[5];
    const float* lin0_b   = (const float*)d_in[6];
    const float* mlp1_W   = (const float*)d_in[7];
    const float* mlp1_b   = (const float*)d_in[8];
    const float* mlp2_W   = (const float*)d_in[9];
    const float* mlp2_b   = (const float*)d_in[10];
    const float* conv_b   = (const float*)d_in[11];
    const float* gru_Wih  = (const float*)d_in[12];
    const float* gru_Whh  = (const float*)d_in[13];
    const float* gru_bih  = (const float*)d_in[14];
    const float* gru_bhh  = (const float*)d_in[15];
    const float* lin1_W   = (const float*)d_in[16];
    const float* lin1_b   = (const float*)d_in[17];
    const float* lin2_W   = (const float*)d_in[18];
    const float* lin2_b   = (const float*)d_in[19];
    const float* l6_W1    = (const float*)d_in[20];
    const float* l6_b1    = (const float*)d_in[21];
    const float* bn_g     = (const float*)d_in[22];
    const float* bn_b     = (const float*)d_in[23];
    const float* l6_W2    = (const float*)d_in[24];
    const float* l6_b2    = (const float*)d_in[25];
    float* out = (float*)d_out;

    // workspace layout
    char* w = (char*)d_ws;
    size_t off = 0;
    auto alloc = [&](size_t bytes) -> void* {
        void* p = w + off;
        off = (off + bytes + 255) & ~(size_t)255;
        return p;
    };
    float* hbuf   = (float*)alloc((size_t)N_ * H_ * 4);
    float* aggm   = (float*)alloc((size_t)N_ * H_ * 4);
    float* outb   = (float*)alloc((size_t)N_ * H_ * 4);
    float* he     = (float*)alloc((size_t)E_ * KH_ * 4);
    float* gi     = (float*)alloc((size_t)N_ * NG_ * 4);
    float* gh     = (float*)alloc((size_t)N_ * NG_ * 4);
    float* h1     = (float*)alloc((size_t)E_ * 128 * 4);
    float* counts = (float*)alloc((size_t)N_ * 4);
    float* mu     = (float*)alloc(128 * 4);
    float* rsig   = (float*)alloc(128 * 4);
    unsigned char* V8      = (unsigned char*)alloc((size_t)N_ * NV_);          // 65.5 MB fp8
    __hip_bfloat16* Abf    = (__hip_bfloat16*)alloc((size_t)MPAD_ * H_ * 2);
    __hip_bfloat16* Mbf    = (__hip_bfloat16*)alloc((size_t)MPAD_ * H_ * 2);
    __hip_bfloat16* Bt     = (__hip_bfloat16*)alloc((size_t)NV_ * H_ * 2);     // 16.8 MB
    __hip_bfloat16* WihB   = (__hip_bfloat16*)alloc((size_t)NG_ * H_ * 2);
    __hip_bfloat16* WhhB   = (__hip_bfloat16*)alloc((size_t)NG_ * H_ * 2);
    __hip_bfloat16* Bpk    = (__hip_bfloat16*)alloc((size_t)384 * 512 * 2);
    __hip_bfloat16* lin2Wb = (__hip_bfloat16*)alloc((size_t)H_ * H_ * 2);
    __hip_bfloat16* BtB    = (__hip_bfloat16*)alloc((size_t)H_ * H_ * 2);
    __hip_bfloat16* Cbf    = (__hip_bfloat16*)alloc((size_t)E_ * 2 * H_ * 2);
    __hip_bfloat16* o1bf   = (__hip_bfloat16*)alloc((size_t)E_ * H_ * 2);

    k_lin0<<<MPAD_, 256, 0, stream>>>(x, pos, emb, lin0_W, lin0_b, hbuf, Abf);
    k_he<<<E_, 128, 0, stream>>>(edge_atr, mlp1_W, mlp1_b, he);
    hipMemsetAsync(counts, 0, (size_t)N_ * 4, stream);
    hipMemsetAsync(aggm, 0, (size_t)N_ * H_ * 4, stream);
    k_counts<<<(E_ + 255) / 256, 256, 0, stream>>>(ei, counts);
    k_trans_bt<<<dim3(NV_ / 64, H_ / 32), 256, 0, stream>>>(mlp2_W, Bt);
    k_prep_w<<<768, 256, 0, stream>>>(gru_Wih, gru_Whh, lin1_W, l6_W1, lin2_W, mlp2_b,
                                      WihB, WhhB, Bpk, lin2Wb, BtB);

    for (int it = 0; it < 3; it++) {
        // fused: gh = Abf@Whh^T + bhh, outb = Abf@BtB^T, V8 = fp8(Abf@Bt^T)
        k_gemm_VP<<<128 + (NV_ / 128) * (MPAD_ / 128), 256, 0, stream>>>(
            Abf, Bt, WhhB, BtB, gru_bhh, gh, outb, V8);
        k_msg<<<E_, 256, 0, stream>>>(ei, he, V8, outb, aggm);
        k_m<<<(N_ * H_ + 255) / 256, 256, 0, stream>>>(aggm, counts, conv_b, Mbf);
        // gi = Mbf @ Wih^T + bih
        k_gemm_nt<256, false, false><<<dim3(6, MPAD_ / 128), 256, 0, stream>>>(
            Mbf, WihB, gi, nullptr, gru_bih, NG_, NG_, N_);
        k_gru_update<<<(N_ * H_ + 255) / 256, 256, 0, stream>>>(gi, gh, hbuf, Abf);
    }

    k_concat<<<E_, 256, 0, stream>>>(ei, hbuf, Cbf);
    k_gemm_tail<<<dim3(3, E_ / 128), 256, 0, stream>>>(Cbf, Bpk, lin1_b, l6_b1, o1bf, h1);
    k_gemm_nt<256, false, false><<<dim3(2, E_ / 128), 256, 0, stream>>>(
        o1bf, lin2Wb, out, nullptr, lin2_b, 242, 242, E_);
    k_bnstats<<<128, 256, 0, stream>>>(h1, mu, rsig);
    k_precs<<<(E_ + 255) / 256, 256, 0, stream>>>(h1, mu, rsig, bn_g, bn_b, l6_W2, l6_b2, out);
}